// Round 1
// baseline (1581.513 us; speedup 1.0000x reference)
//
#include <hip/hip_runtime.h>
#include <hip/hip_bf16.h>
#include <cstdint>
#include <cstddef>

#define NUM_GRAPHS 64
#define HDIM 128

// ---------------------------------------------------------------------------
// CSR build: count in-degree
__global__ __launch_bounds__(256) void count_kernel(const int* __restrict__ dst,
                                                    int* __restrict__ cnt, int E) {
    int i = blockIdx.x * 256 + threadIdx.x;
    if (i < E) atomicAdd(&cnt[dst[i]], 1);
}

// Single-block scan over N counts -> row_ptr (exclusive), fill copy, dis = rsqrt(cnt+1)
__global__ __launch_bounds__(1024) void scan_kernel(const int* __restrict__ cnt,
                                                    int* __restrict__ row_ptr,
                                                    int* __restrict__ fill,
                                                    float* __restrict__ dis,
                                                    int N, int chunk) {
    __shared__ int sums[1024];
    int t = threadIdx.x;
    int beg = t * chunk;
    int end = beg + chunk; if (end > N) end = N;
    int local = 0;
    for (int i = beg; i < end; ++i) local += cnt[i];
    sums[t] = local;
    __syncthreads();
    for (int off = 1; off < 1024; off <<= 1) {
        int v = (t >= off) ? sums[t - off] : 0;
        __syncthreads();
        sums[t] += v;
        __syncthreads();
    }
    int pos = sums[t] - local;  // exclusive prefix
    for (int i = beg; i < end; ++i) {
        int c = cnt[i];
        row_ptr[i] = pos;
        fill[i] = pos;
        dis[i] = rsqrtf((float)c + 1.0f);
        pos += c;
    }
    if (t == 1023) row_ptr[N] = sums[1023];
}

__global__ __launch_bounds__(256) void fill_kernel(const int* __restrict__ src,
                                                   const int* __restrict__ dst,
                                                   int* __restrict__ fill,
                                                   int* __restrict__ sorted_src, int E) {
    int i = blockIdx.x * 256 + threadIdx.x;
    if (i < E) {
        int d = dst[i];
        int p = atomicAdd(&fill[d], 1);
        sorted_src[p] = src[i];
    }
}

// Fold BN(eval)+conv bias into scale/bias per (layer, feature)
__global__ __launch_bounds__(256) void fold_kernel(const float* __restrict__ gamma,
                                                   const float* __restrict__ beta,
                                                   const float* __restrict__ mean,
                                                   const float* __restrict__ var,
                                                   const float* __restrict__ convb,
                                                   float* __restrict__ scale,
                                                   float* __restrict__ bias, int LH) {
    int i = blockIdx.x * 256 + threadIdx.x;
    if (i < LH) {
        float gs = gamma[i] * rsqrtf(var[i] + 1e-5f);
        scale[i] = gs;
        bias[i] = (convb[i] - mean[i]) * gs + beta[i];
    }
}

// ---------------------------------------------------------------------------
// GEMM: out[n] = dis[n] * (h[n] @ W)   [N,128]x[128,128]
// Block 256 threads, 64 nodes/block; thread computes 4 nodes x 8 features.
__global__ __launch_bounds__(256) void gemm_dis_kernel(const float* __restrict__ h,
                                                       const float* __restrict__ W,
                                                       const float* __restrict__ dis,
                                                       float* __restrict__ out, int N) {
    __shared__ float Wl[128 * 128];
    int t = threadIdx.x;
    const float4* W4 = (const float4*)W;
    float4* Wl4 = (float4*)Wl;
#pragma unroll
    for (int i = 0; i < 16; ++i) Wl4[t + 256 * i] = W4[t + 256 * i];
    __syncthreads();

    int fg = t & 15;   // 16 feature groups x 8 feats
    int ng = t >> 4;   // 16 node groups x 4 nodes
    int f0 = fg * 8;
    int n0 = blockIdx.x * 64 + ng * 4;

    float acc[4][8];
#pragma unroll
    for (int i = 0; i < 4; ++i)
#pragma unroll
        for (int j = 0; j < 8; ++j) acc[i][j] = 0.0f;

    for (int k0 = 0; k0 < 128; k0 += 4) {
        float4 hv[4];
#pragma unroll
        for (int i = 0; i < 4; ++i) {
            int n = n0 + i;
            hv[i] = (n < N) ? *(const float4*)&h[(size_t)n * HDIM + k0]
                            : make_float4(0.f, 0.f, 0.f, 0.f);
        }
#pragma unroll
        for (int kk = 0; kk < 4; ++kk) {
            float4 w0 = *(const float4*)&Wl[(k0 + kk) * 128 + f0];
            float4 w1 = *(const float4*)&Wl[(k0 + kk) * 128 + f0 + 4];
#pragma unroll
            for (int i = 0; i < 4; ++i) {
                float hk = ((const float*)&hv[i])[kk];
                acc[i][0] += hk * w0.x; acc[i][1] += hk * w0.y;
                acc[i][2] += hk * w0.z; acc[i][3] += hk * w0.w;
                acc[i][4] += hk * w1.x; acc[i][5] += hk * w1.y;
                acc[i][6] += hk * w1.z; acc[i][7] += hk * w1.w;
            }
        }
    }
#pragma unroll
    for (int i = 0; i < 4; ++i) {
        int n = n0 + i;
        if (n < N) {
            float dn = dis[n];
            float4 o0 = make_float4(acc[i][0] * dn, acc[i][1] * dn, acc[i][2] * dn, acc[i][3] * dn);
            float4 o1 = make_float4(acc[i][4] * dn, acc[i][5] * dn, acc[i][6] * dn, acc[i][7] * dn);
            *(float4*)&out[(size_t)n * HDIM + f0] = o0;
            *(float4*)&out[(size_t)n * HDIM + f0 + 4] = o1;
        }
    }
}

// ---------------------------------------------------------------------------
// Aggregate: hout[n] = relu( (dis[n]*(sum_{e in(n)} hwp[src] + hwp[n])) * scale + bias )
// One wave per node; lane holds 2 features (float2) -> 512B coalesced row reads.
__global__ __launch_bounds__(256) void agg_kernel(const float* __restrict__ hwp,
                                                  const int* __restrict__ row_ptr,
                                                  const int* __restrict__ sorted_src,
                                                  const float* __restrict__ dis,
                                                  const float* __restrict__ scale,
                                                  const float* __restrict__ bias,
                                                  float* __restrict__ hout, int N) {
    int wave = threadIdx.x >> 6;
    int lane = threadIdx.x & 63;
    int n = blockIdx.x * 4 + wave;
    if (n >= N) return;
    const float2* hw2 = (const float2*)hwp;

    float2 acc = hw2[(size_t)n * 64 + lane];  // self term
    int e0 = row_ptr[n];
    int e1 = row_ptr[n + 1];
    int e = e0;
    // unroll by 2 with both loads issued before the adds
    for (; e + 1 < e1; e += 2) {
        int s0 = sorted_src[e];
        int s1 = sorted_src[e + 1];
        float2 v0 = hw2[(size_t)s0 * 64 + lane];
        float2 v1 = hw2[(size_t)s1 * 64 + lane];
        acc.x += v0.x + v1.x;
        acc.y += v0.y + v1.y;
    }
    if (e < e1) {
        int s0 = sorted_src[e];
        float2 v0 = hw2[(size_t)s0 * 64 + lane];
        acc.x += v0.x;
        acc.y += v0.y;
    }
    float dn = dis[n];
    int f0 = lane * 2;
    float y0 = dn * acc.x * scale[f0] + bias[f0];
    float y1 = dn * acc.y * scale[f0 + 1] + bias[f0 + 1];
    float2 o;
    o.x = fmaxf(y0, 0.f);
    o.y = fmaxf(y1, 0.f);
    ((float2*)hout)[(size_t)n * 64 + lane] = o;
}

// ---------------------------------------------------------------------------
// Global add pool using sortedness of batch: per-block register accumulation,
// one atomicAdd per (graph-run, feature).
__global__ __launch_bounds__(128) void pool_kernel(const float* __restrict__ h,
                                                   const int* __restrict__ batch,
                                                   float* __restrict__ pooled, int N) {
    int f = threadIdx.x;
    int n0 = blockIdx.x * 256;
    if (n0 >= N) return;
    int nend = n0 + 256; if (nend > N) nend = N;
    float acc = 0.f;
    int g = batch[n0];
    for (int n = n0; n < nend; ++n) {
        int gn = batch[n];
        if (gn != g) {
            atomicAdd(&pooled[g * HDIM + f], acc);
            acc = 0.f;
            g = gn;
        }
        acc += h[(size_t)n * HDIM + f];
    }
    atomicAdd(&pooled[g * HDIM + f], acc);
}

// ---------------------------------------------------------------------------
// Heads: one block per graph.
__global__ __launch_bounds__(128) void head_kernel(const float* __restrict__ pooled,
                                                   const float* __restrict__ cW1, const float* __restrict__ cb1,
                                                   const float* __restrict__ cW2, const float* __restrict__ cb2,
                                                   const float* __restrict__ nW1, const float* __restrict__ nb1,
                                                   const float* __restrict__ nW2, const float* __restrict__ nb2,
                                                   float* __restrict__ out) {
    __shared__ float p[128];
    __shared__ float hid[128];
    int g = blockIdx.x, t = threadIdx.x;
    p[t] = pooled[g * HDIM + t];
    __syncthreads();

    float a = cb1[t];
    for (int k = 0; k < 128; ++k) a += p[k] * cW1[k * 128 + t];
    hid[t] = fmaxf(a, 0.f);
    __syncthreads();
    if (t < 16) {
        float acc = cb2[t];
        for (int j = 0; j < 128; ++j) acc += hid[j] * cW2[j * 16 + t];
        out[g * 16 + t] = acc;
    }
    __syncthreads();

    float b = nb1[t];
    for (int k = 0; k < 128; ++k) b += p[k] * nW1[k * 128 + t];
    hid[t] = fmaxf(b, 0.f);
    __syncthreads();
    if (t == 0) {
        float acc = nb2[0];
        for (int j = 0; j < 128; ++j) acc += hid[j] * nW2[j];
        out[NUM_GRAPHS * 16 + g] = 1.f / (1.f + expf(-acc));
    }
}

// ---------------------------------------------------------------------------
extern "C" void kernel_launch(void* const* d_in, const int* in_sizes, int n_in,
                              void* d_out, int out_size, void* d_ws, size_t ws_size,
                              hipStream_t stream) {
    const float* x       = (const float*)d_in[0];
    const int*   ei      = (const int*)d_in[1];
    const int*   batch   = (const int*)d_in[2];
    const float* conv_W  = (const float*)d_in[3];
    const float* conv_b  = (const float*)d_in[4];
    const float* bn_g    = (const float*)d_in[5];
    const float* bn_b    = (const float*)d_in[6];
    const float* bn_m    = (const float*)d_in[7];
    const float* bn_v    = (const float*)d_in[8];
    const float* cW1     = (const float*)d_in[9];
    const float* cb1     = (const float*)d_in[10];
    const float* cW2     = (const float*)d_in[11];
    const float* cb2     = (const float*)d_in[12];
    const float* nW1     = (const float*)d_in[13];
    const float* nb1     = (const float*)d_in[14];
    const float* nW2     = (const float*)d_in[15];
    const float* nb2     = (const float*)d_in[16];

    const int N = in_sizes[2];
    const int E = in_sizes[1] / 2;
    const int L = in_sizes[3] / (128 * 128);
    const int H = HDIM;

    const int* src = ei;
    const int* dst = ei + E;

    char* w = (char*)d_ws;
    size_t o = 0;
    auto alloc = [&](size_t bytes) -> void* {
        void* p = w + o;
        o = (o + bytes + 255) & ~(size_t)255;
        return p;
    };
    int*   cnt        = (int*)alloc((size_t)N * 4);
    int*   fill       = (int*)alloc((size_t)N * 4);
    int*   row_ptr    = (int*)alloc((size_t)(N + 1) * 4);
    float* dis        = (float*)alloc((size_t)N * 4);
    float* scale      = (float*)alloc((size_t)L * H * 4);
    float* bias       = (float*)alloc((size_t)L * H * 4);
    int*   sorted_src = (int*)alloc((size_t)E * 4);
    float* bufA       = (float*)alloc((size_t)N * H * 4);  // hw' (GEMM out)
    float* bufB       = (float*)alloc((size_t)N * H * 4);  // h (layer out)
    float* pooled     = (float*)alloc((size_t)NUM_GRAPHS * H * 4);

    hipMemsetAsync(cnt, 0, (size_t)N * 4, stream);
    hipMemsetAsync(pooled, 0, (size_t)NUM_GRAPHS * H * 4, stream);

    count_kernel<<<(E + 255) / 256, 256, 0, stream>>>(dst, cnt, E);
    int chunk = (N + 1023) / 1024;
    scan_kernel<<<1, 1024, 0, stream>>>(cnt, row_ptr, fill, dis, N, chunk);
    fill_kernel<<<(E + 255) / 256, 256, 0, stream>>>(src, dst, fill, sorted_src, E);
    fold_kernel<<<(L * H + 255) / 256, 256, 0, stream>>>(bn_g, bn_b, bn_m, bn_v, conv_b,
                                                         scale, bias, L * H);

    const float* hin = x;
    for (int l = 0; l < L; ++l) {
        gemm_dis_kernel<<<(N + 63) / 64, 256, 0, stream>>>(hin, conv_W + (size_t)l * H * H,
                                                           dis, bufA, N);
        agg_kernel<<<(N + 3) / 4, 256, 0, stream>>>(bufA, row_ptr, sorted_src, dis,
                                                    scale + l * H, bias + l * H, bufB, N);
        hin = bufB;
    }

    pool_kernel<<<(N + 255) / 256, 128, 0, stream>>>(bufB, batch, pooled, N);
    head_kernel<<<NUM_GRAPHS, 128, 0, stream>>>(pooled, cW1, cb1, cW2, cb2,
                                                nW1, nb1, nW2, nb2, (float*)d_out);
}

// Round 2
// 1329.595 us; speedup vs baseline: 1.1895x; 1.1895x over previous
//
#include <hip/hip_runtime.h>
#include <hip/hip_bf16.h>
#include <cstdint>
#include <cstddef>

#define NUM_GRAPHS 64
#define HDIM 128

// ---------------------------------------------------------------------------
// CSR build: count in-degree
__global__ __launch_bounds__(256) void count_kernel(const int* __restrict__ dst,
                                                    int* __restrict__ cnt, int E) {
    int i = blockIdx.x * 256 + threadIdx.x;
    if (i < E) atomicAdd(&cnt[dst[i]], 1);
}

// --- hierarchical scan: partial sums per 4096-chunk ---
__global__ __launch_bounds__(256) void scan_partial_kernel(const int* __restrict__ cnt,
                                                           int* __restrict__ blockSums, int N) {
    __shared__ int s[256];
    int t = threadIdx.x;
    int base = blockIdx.x * 4096 + t * 16;
    int local = 0;
#pragma unroll
    for (int i = 0; i < 16; ++i) {
        int idx = base + i;
        if (idx < N) local += cnt[idx];
    }
    s[t] = local;
    __syncthreads();
    for (int off = 128; off > 0; off >>= 1) {
        if (t < off) s[t] += s[t + off];
        __syncthreads();
    }
    if (t == 0) blockSums[blockIdx.x] = s[0];
}

// --- scan the (<=1024) block sums in one tiny block; also set row_ptr[N]=E ---
__global__ __launch_bounds__(1024) void scan_blocksums_kernel(int* __restrict__ blockSums,
                                                              int* __restrict__ row_ptr,
                                                              int nb, int E, int N) {
    __shared__ int s[1024];
    int t = threadIdx.x;
    int v = (t < nb) ? blockSums[t] : 0;
    s[t] = v;
    __syncthreads();
    for (int off = 1; off < 1024; off <<= 1) {
        int u = (t >= off) ? s[t - off] : 0;
        __syncthreads();
        s[t] += u;
        __syncthreads();
    }
    if (t < nb) blockSums[t] = s[t] - v;  // exclusive
    if (t == 0) row_ptr[N] = E;
}

// --- apply: per-chunk exclusive prefix + row_ptr/fill/dis ---
__global__ __launch_bounds__(256) void scan_apply_kernel(const int* __restrict__ cnt,
                                                         const int* __restrict__ blockSums,
                                                         int* __restrict__ row_ptr,
                                                         int* __restrict__ fill,
                                                         float* __restrict__ dis, int N) {
    __shared__ int s[256];
    int t = threadIdx.x;
    int base = blockIdx.x * 4096 + t * 16;
    int c[16];
    int local = 0;
#pragma unroll
    for (int i = 0; i < 16; ++i) {
        int idx = base + i;
        c[i] = (idx < N) ? cnt[idx] : 0;
        local += c[i];
    }
    s[t] = local;
    __syncthreads();
    for (int off = 1; off < 256; off <<= 1) {
        int u = (t >= off) ? s[t - off] : 0;
        __syncthreads();
        s[t] += u;
        __syncthreads();
    }
    int pos = blockSums[blockIdx.x] + s[t] - local;  // exclusive prefix for this thread
#pragma unroll
    for (int i = 0; i < 16; ++i) {
        int idx = base + i;
        if (idx < N) {
            row_ptr[idx] = pos;
            fill[idx] = pos;
            dis[idx] = rsqrtf((float)c[i] + 1.0f);
            pos += c[i];
        }
    }
}

__global__ __launch_bounds__(256) void fill_kernel(const int* __restrict__ src,
                                                   const int* __restrict__ dst,
                                                   int* __restrict__ fill,
                                                   int* __restrict__ sorted_src, int E) {
    int i = blockIdx.x * 256 + threadIdx.x;
    if (i < E) {
        int d = dst[i];
        int p = atomicAdd(&fill[d], 1);
        sorted_src[p] = src[i];
    }
}

// Fold BN(eval)+conv bias into scale/bias per (layer, feature)
__global__ __launch_bounds__(256) void fold_kernel(const float* __restrict__ gamma,
                                                   const float* __restrict__ beta,
                                                   const float* __restrict__ mean,
                                                   const float* __restrict__ var,
                                                   const float* __restrict__ convb,
                                                   float* __restrict__ scale,
                                                   float* __restrict__ bias, int LH) {
    int i = blockIdx.x * 256 + threadIdx.x;
    if (i < LH) {
        float gs = gamma[i] * rsqrtf(var[i] + 1e-5f);
        scale[i] = gs;
        bias[i] = (convb[i] - mean[i]) * gs + beta[i];
    }
}

// ---------------------------------------------------------------------------
// GEMM: out[n] = dis[n] * (h[n] @ W)   [N,128]x[128,128]
__global__ __launch_bounds__(256) void gemm_dis_kernel(const float* __restrict__ h,
                                                       const float* __restrict__ W,
                                                       const float* __restrict__ dis,
                                                       float* __restrict__ out, int N) {
    __shared__ float Wl[128 * 128];
    int t = threadIdx.x;
    const float4* W4 = (const float4*)W;
    float4* Wl4 = (float4*)Wl;
#pragma unroll
    for (int i = 0; i < 16; ++i) Wl4[t + 256 * i] = W4[t + 256 * i];
    __syncthreads();

    int fg = t & 15;   // 16 feature groups x 8 feats
    int ng = t >> 4;   // 16 node groups x 4 nodes
    int f0 = fg * 8;
    int n0 = blockIdx.x * 64 + ng * 4;

    float acc[4][8];
#pragma unroll
    for (int i = 0; i < 4; ++i)
#pragma unroll
        for (int j = 0; j < 8; ++j) acc[i][j] = 0.0f;

    for (int k0 = 0; k0 < 128; k0 += 4) {
        float4 hv[4];
#pragma unroll
        for (int i = 0; i < 4; ++i) {
            int n = n0 + i;
            hv[i] = (n < N) ? *(const float4*)&h[(size_t)n * HDIM + k0]
                            : make_float4(0.f, 0.f, 0.f, 0.f);
        }
#pragma unroll
        for (int kk = 0; kk < 4; ++kk) {
            float4 w0 = *(const float4*)&Wl[(k0 + kk) * 128 + f0];
            float4 w1 = *(const float4*)&Wl[(k0 + kk) * 128 + f0 + 4];
#pragma unroll
            for (int i = 0; i < 4; ++i) {
                float hk = ((const float*)&hv[i])[kk];
                acc[i][0] += hk * w0.x; acc[i][1] += hk * w0.y;
                acc[i][2] += hk * w0.z; acc[i][3] += hk * w0.w;
                acc[i][4] += hk * w1.x; acc[i][5] += hk * w1.y;
                acc[i][6] += hk * w1.z; acc[i][7] += hk * w1.w;
            }
        }
    }
#pragma unroll
    for (int i = 0; i < 4; ++i) {
        int n = n0 + i;
        if (n < N) {
            float dn = dis[n];
            float4 o0 = make_float4(acc[i][0] * dn, acc[i][1] * dn, acc[i][2] * dn, acc[i][3] * dn);
            float4 o1 = make_float4(acc[i][4] * dn, acc[i][5] * dn, acc[i][6] * dn, acc[i][7] * dn);
            *(float4*)&out[(size_t)n * HDIM + f0] = o0;
            *(float4*)&out[(size_t)n * HDIM + f0 + 4] = o1;
        }
    }
}

// ---------------------------------------------------------------------------
// Aggregate: hout[n] = relu( (dis[n]*(sum_{e in(n)} hwp[src] + hwp[n])) * scale + bias )
__global__ __launch_bounds__(256) void agg_kernel(const float* __restrict__ hwp,
                                                  const int* __restrict__ row_ptr,
                                                  const int* __restrict__ sorted_src,
                                                  const float* __restrict__ dis,
                                                  const float* __restrict__ scale,
                                                  const float* __restrict__ bias,
                                                  float* __restrict__ hout, int N) {
    int wave = threadIdx.x >> 6;
    int lane = threadIdx.x & 63;
    int n = blockIdx.x * 4 + wave;
    if (n >= N) return;
    const float2* hw2 = (const float2*)hwp;

    float2 acc = hw2[(size_t)n * 64 + lane];  // self term
    int e0 = row_ptr[n];
    int e1 = row_ptr[n + 1];
    int e = e0;
    for (; e + 1 < e1; e += 2) {
        int s0 = sorted_src[e];
        int s1 = sorted_src[e + 1];
        float2 v0 = hw2[(size_t)s0 * 64 + lane];
        float2 v1 = hw2[(size_t)s1 * 64 + lane];
        acc.x += v0.x + v1.x;
        acc.y += v0.y + v1.y;
    }
    if (e < e1) {
        int s0 = sorted_src[e];
        float2 v0 = hw2[(size_t)s0 * 64 + lane];
        acc.x += v0.x;
        acc.y += v0.y;
    }
    float dn = dis[n];
    int f0 = lane * 2;
    float y0 = dn * acc.x * scale[f0] + bias[f0];
    float y1 = dn * acc.y * scale[f0 + 1] + bias[f0 + 1];
    float2 o;
    o.x = fmaxf(y0, 0.f);
    o.y = fmaxf(y1, 0.f);
    ((float2*)hout)[(size_t)n * 64 + lane] = o;
}

// ---------------------------------------------------------------------------
// Global add pool using sortedness of batch.
__global__ __launch_bounds__(128) void pool_kernel(const float* __restrict__ h,
                                                   const int* __restrict__ batch,
                                                   float* __restrict__ pooled, int N) {
    int f = threadIdx.x;
    int n0 = blockIdx.x * 256;
    if (n0 >= N) return;
    int nend = n0 + 256; if (nend > N) nend = N;
    float acc = 0.f;
    int g = batch[n0];
    for (int n = n0; n < nend; ++n) {
        int gn = batch[n];
        if (gn != g) {
            atomicAdd(&pooled[g * HDIM + f], acc);
            acc = 0.f;
            g = gn;
        }
        acc += h[(size_t)n * HDIM + f];
    }
    atomicAdd(&pooled[g * HDIM + f], acc);
}

// ---------------------------------------------------------------------------
// Heads: one block per graph.
__global__ __launch_bounds__(128) void head_kernel(const float* __restrict__ pooled,
                                                   const float* __restrict__ cW1, const float* __restrict__ cb1,
                                                   const float* __restrict__ cW2, const float* __restrict__ cb2,
                                                   const float* __restrict__ nW1, const float* __restrict__ nb1,
                                                   const float* __restrict__ nW2, const float* __restrict__ nb2,
                                                   float* __restrict__ out) {
    __shared__ float p[128];
    __shared__ float hid[128];
    int g = blockIdx.x, t = threadIdx.x;
    p[t] = pooled[g * HDIM + t];
    __syncthreads();

    float a = cb1[t];
    for (int k = 0; k < 128; ++k) a += p[k] * cW1[k * 128 + t];
    hid[t] = fmaxf(a, 0.f);
    __syncthreads();
    if (t < 16) {
        float acc = cb2[t];
        for (int j = 0; j < 128; ++j) acc += hid[j] * cW2[j * 16 + t];
        out[g * 16 + t] = acc;
    }
    __syncthreads();

    float b = nb1[t];
    for (int k = 0; k < 128; ++k) b += p[k] * nW1[k * 128 + t];
    hid[t] = fmaxf(b, 0.f);
    __syncthreads();
    if (t == 0) {
        float acc = nb2[0];
        for (int j = 0; j < 128; ++j) acc += hid[j] * nW2[j];
        out[NUM_GRAPHS * 16 + g] = 1.f / (1.f + expf(-acc));
    }
}

// ---------------------------------------------------------------------------
extern "C" void kernel_launch(void* const* d_in, const int* in_sizes, int n_in,
                              void* d_out, int out_size, void* d_ws, size_t ws_size,
                              hipStream_t stream) {
    const float* x       = (const float*)d_in[0];
    const int*   ei      = (const int*)d_in[1];
    const int*   batch   = (const int*)d_in[2];
    const float* conv_W  = (const float*)d_in[3];
    const float* conv_b  = (const float*)d_in[4];
    const float* bn_g    = (const float*)d_in[5];
    const float* bn_b    = (const float*)d_in[6];
    const float* bn_m    = (const float*)d_in[7];
    const float* bn_v    = (const float*)d_in[8];
    const float* cW1     = (const float*)d_in[9];
    const float* cb1     = (const float*)d_in[10];
    const float* cW2     = (const float*)d_in[11];
    const float* cb2     = (const float*)d_in[12];
    const float* nW1     = (const float*)d_in[13];
    const float* nb1     = (const float*)d_in[14];
    const float* nW2     = (const float*)d_in[15];
    const float* nb2     = (const float*)d_in[16];

    const int N = in_sizes[2];
    const int E = in_sizes[1] / 2;
    const int L = in_sizes[3] / (128 * 128);
    const int H = HDIM;

    const int* src = ei;
    const int* dst = ei + E;

    char* w = (char*)d_ws;
    size_t o = 0;
    auto alloc = [&](size_t bytes) -> void* {
        void* p = w + o;
        o = (o + bytes + 255) & ~(size_t)255;
        return p;
    };
    int nscan = (N + 4095) / 4096;  // chunks of 4096 for hierarchical scan
    int*   cnt        = (int*)alloc((size_t)N * 4);
    int*   fill       = (int*)alloc((size_t)N * 4);
    int*   row_ptr    = (int*)alloc((size_t)(N + 1) * 4);
    float* dis        = (float*)alloc((size_t)N * 4);
    float* scale      = (float*)alloc((size_t)L * H * 4);
    float* bias       = (float*)alloc((size_t)L * H * 4);
    int*   blockSums  = (int*)alloc((size_t)nscan * 4);
    int*   sorted_src = (int*)alloc((size_t)E * 4);
    float* bufA       = (float*)alloc((size_t)N * H * 4);  // hw' (GEMM out)
    float* bufB       = (float*)alloc((size_t)N * H * 4);  // h (layer out)
    float* pooled     = (float*)alloc((size_t)NUM_GRAPHS * H * 4);

    hipMemsetAsync(cnt, 0, (size_t)N * 4, stream);
    hipMemsetAsync(pooled, 0, (size_t)NUM_GRAPHS * H * 4, stream);

    count_kernel<<<(E + 255) / 256, 256, 0, stream>>>(dst, cnt, E);
    scan_partial_kernel<<<nscan, 256, 0, stream>>>(cnt, blockSums, N);
    scan_blocksums_kernel<<<1, 1024, 0, stream>>>(blockSums, row_ptr, nscan, E, N);
    scan_apply_kernel<<<nscan, 256, 0, stream>>>(cnt, blockSums, row_ptr, fill, dis, N);
    fill_kernel<<<(E + 255) / 256, 256, 0, stream>>>(src, dst, fill, sorted_src, E);
    fold_kernel<<<(L * H + 255) / 256, 256, 0, stream>>>(bn_g, bn_b, bn_m, bn_v, conv_b,
                                                         scale, bias, L * H);

    const float* hin = x;
    for (int l = 0; l < L; ++l) {
        gemm_dis_kernel<<<(N + 63) / 64, 256, 0, stream>>>(hin, conv_W + (size_t)l * H * H,
                                                           dis, bufA, N);
        agg_kernel<<<(N + 3) / 4, 256, 0, stream>>>(bufA, row_ptr, sorted_src, dis,
                                                    scale + l * H, bias + l * H, bufB, N);
        hin = bufB;
    }

    pool_kernel<<<(N + 255) / 256, 128, 0, stream>>>(bufB, batch, pooled, N);
    head_kernel<<<NUM_GRAPHS, 128, 0, stream>>>(pooled, cW1, cb1, cW2, cb2,
                                                nW1, nb1, nW2, nb2, (float*)d_out);
}

// Round 3
// 1024.138 us; speedup vs baseline: 1.5442x; 1.2983x over previous
//
#include <hip/hip_runtime.h>
#include <hip/hip_bf16.h>
#include <cstdint>
#include <cstddef>

#define NUM_GRAPHS 64
#define HDIM 128

typedef __attribute__((ext_vector_type(8))) short short8v;
typedef __attribute__((ext_vector_type(4))) float float4v;

__device__ inline unsigned short f2bf_rne(float f) {
    unsigned u = __float_as_uint(f);
    unsigned r = u + 0x7fffu + ((u >> 16) & 1u);
    return (unsigned short)(r >> 16);
}

// ---------------------------------------------------------------------------
// CSR build: count in-degree
__global__ __launch_bounds__(256) void count_kernel(const int* __restrict__ dst,
                                                    int* __restrict__ cnt, int E) {
    int i = blockIdx.x * 256 + threadIdx.x;
    if (i < E) atomicAdd(&cnt[dst[i]], 1);
}

// --- hierarchical scan: partial sums per 4096-chunk ---
__global__ __launch_bounds__(256) void scan_partial_kernel(const int* __restrict__ cnt,
                                                           int* __restrict__ blockSums, int N) {
    __shared__ int s[256];
    int t = threadIdx.x;
    int base = blockIdx.x * 4096 + t * 16;
    int local = 0;
#pragma unroll
    for (int i = 0; i < 16; ++i) {
        int idx = base + i;
        if (idx < N) local += cnt[idx];
    }
    s[t] = local;
    __syncthreads();
    for (int off = 128; off > 0; off >>= 1) {
        if (t < off) s[t] += s[t + off];
        __syncthreads();
    }
    if (t == 0) blockSums[blockIdx.x] = s[0];
}

__global__ __launch_bounds__(1024) void scan_blocksums_kernel(int* __restrict__ blockSums,
                                                              int* __restrict__ row_ptr,
                                                              int nb, int E, int N) {
    __shared__ int s[1024];
    int t = threadIdx.x;
    int v = (t < nb) ? blockSums[t] : 0;
    s[t] = v;
    __syncthreads();
    for (int off = 1; off < 1024; off <<= 1) {
        int u = (t >= off) ? s[t - off] : 0;
        __syncthreads();
        s[t] += u;
        __syncthreads();
    }
    if (t < nb) blockSums[t] = s[t] - v;  // exclusive
    if (t == 0) row_ptr[N] = E;
}

__global__ __launch_bounds__(256) void scan_apply_kernel(const int* __restrict__ cnt,
                                                         const int* __restrict__ blockSums,
                                                         int* __restrict__ row_ptr,
                                                         int* __restrict__ fill,
                                                         float* __restrict__ dis, int N) {
    __shared__ int s[256];
    int t = threadIdx.x;
    int base = blockIdx.x * 4096 + t * 16;
    int c[16];
    int local = 0;
#pragma unroll
    for (int i = 0; i < 16; ++i) {
        int idx = base + i;
        c[i] = (idx < N) ? cnt[idx] : 0;
        local += c[i];
    }
    s[t] = local;
    __syncthreads();
    for (int off = 1; off < 256; off <<= 1) {
        int u = (t >= off) ? s[t - off] : 0;
        __syncthreads();
        s[t] += u;
        __syncthreads();
    }
    int pos = blockSums[blockIdx.x] + s[t] - local;
#pragma unroll
    for (int i = 0; i < 16; ++i) {
        int idx = base + i;
        if (idx < N) {
            row_ptr[idx] = pos;
            fill[idx] = pos;
            dis[idx] = rsqrtf((float)c[i] + 1.0f);
            pos += c[i];
        }
    }
}

__global__ __launch_bounds__(256) void fill_kernel(const int* __restrict__ src,
                                                   const int* __restrict__ dst,
                                                   int* __restrict__ fill,
                                                   int* __restrict__ sorted_src, int E) {
    int i = blockIdx.x * 256 + threadIdx.x;
    if (i < E) {
        int d = dst[i];
        int p = atomicAdd(&fill[d], 1);
        sorted_src[p] = src[i];
    }
}

// Fold BN(eval)+conv bias into scale/bias per (layer, feature)
__global__ __launch_bounds__(256) void fold_kernel(const float* __restrict__ gamma,
                                                   const float* __restrict__ beta,
                                                   const float* __restrict__ mean,
                                                   const float* __restrict__ var,
                                                   const float* __restrict__ convb,
                                                   float* __restrict__ scale,
                                                   float* __restrict__ bias, int LH) {
    int i = blockIdx.x * 256 + threadIdx.x;
    if (i < LH) {
        float gs = gamma[i] * rsqrtf(var[i] + 1e-5f);
        scale[i] = gs;
        bias[i] = (convb[i] - mean[i]) * gs + beta[i];
    }
}

// ---------------------------------------------------------------------------
// Pack W[l] into MFMA B-fragment layout, split hi/lo bf16.
// Fragment: B[k][n] with n = ntile*16 + (lane&15), k = kchunk*32 + (lane>>4)*8 + j
// Stored at [((l*8+ntile)*4 + kchunk)*64 + lane]*8 + j
__global__ __launch_bounds__(64) void pack_W_kernel(const float* __restrict__ W,
                                                    short* __restrict__ hi,
                                                    short* __restrict__ lo) {
    int b = blockIdx.x;         // l*32 + ntile*4 + kchunk
    int l = b >> 5;
    int ntile = (b >> 2) & 7;
    int kchunk = b & 3;
    int lane = threadIdx.x;
    int n = ntile * 16 + (lane & 15);
    int kbase = kchunk * 32 + (lane >> 4) * 8;
    size_t ob = ((size_t)b * 64 + lane) * 8;
#pragma unroll
    for (int j = 0; j < 8; ++j) {
        float w = W[(size_t)l * 16384 + (size_t)(kbase + j) * 128 + n];
        unsigned short hb = f2bf_rne(w);
        float hif = __uint_as_float((unsigned)hb << 16);
        hi[ob + j] = (short)hb;
        lo[ob + j] = (short)f2bf_rne(w - hif);
    }
}

// ---------------------------------------------------------------------------
// MFMA GEMM (bf16x3 split): out[n] = dis[n] * (h[n] @ W)  [N,128]x[128,128]
// Block: 256 thr = 4 waves; wave handles 32 node-rows x 128 feats.
// A frag: lane holds h[mbase+mt*16+(lane&15)][kc*32+(lane>>4)*8+j]
// D: node row = mbase+mt*16+(lane>>4)*4+r, feat = nt*16+(lane&15)   [m89]
__global__ __launch_bounds__(256) void gemm_mfma_kernel(const float* __restrict__ h,
                                                        const short* __restrict__ Whi,
                                                        const short* __restrict__ Wlo,
                                                        const float* __restrict__ dis,
                                                        float* __restrict__ out, int N) {
    int wave = threadIdx.x >> 6;
    int lane = threadIdx.x & 63;
    int lrow = lane & 15;
    int lk8 = lane >> 4;
    int mbase = blockIdx.x * 128 + wave * 32;

    float4v acc[2][8];
#pragma unroll
    for (int mt = 0; mt < 2; ++mt)
#pragma unroll
        for (int nt = 0; nt < 8; ++nt) {
            acc[mt][nt][0] = 0.f; acc[mt][nt][1] = 0.f;
            acc[mt][nt][2] = 0.f; acc[mt][nt][3] = 0.f;
        }

    const short8v* BH = (const short8v*)Whi;
    const short8v* BL = (const short8v*)Wlo;

    for (int kc = 0; kc < 4; ++kc) {
        short8v ahi[2], alo[2];
#pragma unroll
        for (int mt = 0; mt < 2; ++mt) {
            int node = mbase + mt * 16 + lrow;
            float av[8];
            if (node < N) {
                const float4* hp = (const float4*)&h[(size_t)node * HDIM + kc * 32 + lk8 * 8];
                float4 f0 = hp[0], f1 = hp[1];
                av[0] = f0.x; av[1] = f0.y; av[2] = f0.z; av[3] = f0.w;
                av[4] = f1.x; av[5] = f1.y; av[6] = f1.z; av[7] = f1.w;
            } else {
#pragma unroll
                for (int j = 0; j < 8; ++j) av[j] = 0.f;
            }
#pragma unroll
            for (int j = 0; j < 8; ++j) {
                unsigned short hb = f2bf_rne(av[j]);
                float hif = __uint_as_float((unsigned)hb << 16);
                ahi[mt][j] = (short)hb;
                alo[mt][j] = (short)f2bf_rne(av[j] - hif);
            }
        }
#pragma unroll
        for (int nt = 0; nt < 8; ++nt) {
            short8v bhi = BH[(size_t)(nt * 4 + kc) * 64 + lane];
            short8v blo = BL[(size_t)(nt * 4 + kc) * 64 + lane];
#pragma unroll
            for (int mt = 0; mt < 2; ++mt) {
                acc[mt][nt] = __builtin_amdgcn_mfma_f32_16x16x32_bf16(ahi[mt], bhi, acc[mt][nt], 0, 0, 0);
                acc[mt][nt] = __builtin_amdgcn_mfma_f32_16x16x32_bf16(ahi[mt], blo, acc[mt][nt], 0, 0, 0);
                acc[mt][nt] = __builtin_amdgcn_mfma_f32_16x16x32_bf16(alo[mt], bhi, acc[mt][nt], 0, 0, 0);
            }
        }
    }

#pragma unroll
    for (int mt = 0; mt < 2; ++mt) {
#pragma unroll
        for (int r = 0; r < 4; ++r) {
            int node = mbase + mt * 16 + lk8 * 4 + r;
            if (node < N) {
                float dn = dis[node];
#pragma unroll
                for (int nt = 0; nt < 8; ++nt)
                    out[(size_t)node * HDIM + nt * 16 + lrow] = acc[mt][nt][r] * dn;
            }
        }
    }
}

// ---------------------------------------------------------------------------
// Aggregate: hout[n] = relu( (dis[n]*(sum_{e in(n)} hwp[src] + hwp[n])) * scale + bias )
__global__ __launch_bounds__(256) void agg_kernel(const float* __restrict__ hwp,
                                                  const int* __restrict__ row_ptr,
                                                  const int* __restrict__ sorted_src,
                                                  const float* __restrict__ dis,
                                                  const float* __restrict__ scale,
                                                  const float* __restrict__ bias,
                                                  float* __restrict__ hout, int N) {
    int wave = threadIdx.x >> 6;
    int lane = threadIdx.x & 63;
    int n = blockIdx.x * 4 + wave;
    if (n >= N) return;
    const float2* hw2 = (const float2*)hwp;

    float2 acc = hw2[(size_t)n * 64 + lane];  // self term
    int e0 = row_ptr[n];
    int e1 = row_ptr[n + 1];
    int e = e0;
    for (; e + 3 < e1; e += 4) {
        int s0 = sorted_src[e];
        int s1 = sorted_src[e + 1];
        int s2 = sorted_src[e + 2];
        int s3 = sorted_src[e + 3];
        float2 v0 = hw2[(size_t)s0 * 64 + lane];
        float2 v1 = hw2[(size_t)s1 * 64 + lane];
        float2 v2 = hw2[(size_t)s2 * 64 + lane];
        float2 v3 = hw2[(size_t)s3 * 64 + lane];
        acc.x += v0.x + v1.x + v2.x + v3.x;
        acc.y += v0.y + v1.y + v2.y + v3.y;
    }
    for (; e < e1; ++e) {
        int s0 = sorted_src[e];
        float2 v0 = hw2[(size_t)s0 * 64 + lane];
        acc.x += v0.x;
        acc.y += v0.y;
    }
    float dn = dis[n];
    int f0 = lane * 2;
    float y0 = dn * acc.x * scale[f0] + bias[f0];
    float y1 = dn * acc.y * scale[f0 + 1] + bias[f0 + 1];
    float2 o;
    o.x = fmaxf(y0, 0.f);
    o.y = fmaxf(y1, 0.f);
    ((float2*)hout)[(size_t)n * 64 + lane] = o;
}

// ---------------------------------------------------------------------------
// Global add pool using sortedness of batch.
__global__ __launch_bounds__(128) void pool_kernel(const float* __restrict__ h,
                                                   const int* __restrict__ batch,
                                                   float* __restrict__ pooled, int N) {
    int f = threadIdx.x;
    int n0 = blockIdx.x * 256;
    if (n0 >= N) return;
    int nend = n0 + 256; if (nend > N) nend = N;
    float acc = 0.f;
    int g = batch[n0];
    for (int n = n0; n < nend; ++n) {
        int gn = batch[n];
        if (gn != g) {
            atomicAdd(&pooled[g * HDIM + f], acc);
            acc = 0.f;
            g = gn;
        }
        acc += h[(size_t)n * HDIM + f];
    }
    atomicAdd(&pooled[g * HDIM + f], acc);
}

// ---------------------------------------------------------------------------
// Heads: one block per graph.
__global__ __launch_bounds__(128) void head_kernel(const float* __restrict__ pooled,
                                                   const float* __restrict__ cW1, const float* __restrict__ cb1,
                                                   const float* __restrict__ cW2, const float* __restrict__ cb2,
                                                   const float* __restrict__ nW1, const float* __restrict__ nb1,
                                                   const float* __restrict__ nW2, const float* __restrict__ nb2,
                                                   float* __restrict__ out) {
    __shared__ float p[128];
    __shared__ float hid[128];
    int g = blockIdx.x, t = threadIdx.x;
    p[t] = pooled[g * HDIM + t];
    __syncthreads();

    float a = cb1[t];
    for (int k = 0; k < 128; ++k) a += p[k] * cW1[k * 128 + t];
    hid[t] = fmaxf(a, 0.f);
    __syncthreads();
    if (t < 16) {
        float acc = cb2[t];
        for (int j = 0; j < 128; ++j) acc += hid[j] * cW2[j * 16 + t];
        out[g * 16 + t] = acc;
    }
    __syncthreads();

    float b = nb1[t];
    for (int k = 0; k < 128; ++k) b += p[k] * nW1[k * 128 + t];
    hid[t] = fmaxf(b, 0.f);
    __syncthreads();
    if (t == 0) {
        float acc = nb2[0];
        for (int j = 0; j < 128; ++j) acc += hid[j] * nW2[j];
        out[NUM_GRAPHS * 16 + g] = 1.f / (1.f + expf(-acc));
    }
}

// ---------------------------------------------------------------------------
extern "C" void kernel_launch(void* const* d_in, const int* in_sizes, int n_in,
                              void* d_out, int out_size, void* d_ws, size_t ws_size,
                              hipStream_t stream) {
    const float* x       = (const float*)d_in[0];
    const int*   ei      = (const int*)d_in[1];
    const int*   batch   = (const int*)d_in[2];
    const float* conv_W  = (const float*)d_in[3];
    const float* conv_b  = (const float*)d_in[4];
    const float* bn_g    = (const float*)d_in[5];
    const float* bn_b    = (const float*)d_in[6];
    const float* bn_m    = (const float*)d_in[7];
    const float* bn_v    = (const float*)d_in[8];
    const float* cW1     = (const float*)d_in[9];
    const float* cb1     = (const float*)d_in[10];
    const float* cW2     = (const float*)d_in[11];
    const float* cb2     = (const float*)d_in[12];
    const float* nW1     = (const float*)d_in[13];
    const float* nb1     = (const float*)d_in[14];
    const float* nW2     = (const float*)d_in[15];
    const float* nb2     = (const float*)d_in[16];

    const int N = in_sizes[2];
    const int E = in_sizes[1] / 2;
    const int L = in_sizes[3] / (128 * 128);
    const int H = HDIM;

    const int* src = ei;
    const int* dst = ei + E;

    char* w = (char*)d_ws;
    size_t o = 0;
    auto alloc = [&](size_t bytes) -> void* {
        void* p = w + o;
        o = (o + bytes + 255) & ~(size_t)255;
        return p;
    };
    int nscan = (N + 4095) / 4096;
    int*   cnt        = (int*)alloc((size_t)N * 4);
    int*   fill       = (int*)alloc((size_t)N * 4);
    int*   row_ptr    = (int*)alloc((size_t)(N + 1) * 4);
    float* dis        = (float*)alloc((size_t)N * 4);
    float* scale      = (float*)alloc((size_t)L * H * 4);
    float* bias       = (float*)alloc((size_t)L * H * 4);
    int*   blockSums  = (int*)alloc((size_t)nscan * 4);
    short* Whi        = (short*)alloc((size_t)L * H * H * 2);
    short* Wlo        = (short*)alloc((size_t)L * H * H * 2);
    int*   sorted_src = (int*)alloc((size_t)E * 4);
    float* bufA       = (float*)alloc((size_t)N * H * 4);
    float* bufB       = (float*)alloc((size_t)N * H * 4);
    float* pooled     = (float*)alloc((size_t)NUM_GRAPHS * H * 4);

    hipMemsetAsync(cnt, 0, (size_t)N * 4, stream);
    hipMemsetAsync(pooled, 0, (size_t)NUM_GRAPHS * H * 4, stream);

    count_kernel<<<(E + 255) / 256, 256, 0, stream>>>(dst, cnt, E);
    scan_partial_kernel<<<nscan, 256, 0, stream>>>(cnt, blockSums, N);
    scan_blocksums_kernel<<<1, 1024, 0, stream>>>(blockSums, row_ptr, nscan, E, N);
    scan_apply_kernel<<<nscan, 256, 0, stream>>>(cnt, blockSums, row_ptr, fill, dis, N);
    fill_kernel<<<(E + 255) / 256, 256, 0, stream>>>(src, dst, fill, sorted_src, E);
    fold_kernel<<<(L * H + 255) / 256, 256, 0, stream>>>(bn_g, bn_b, bn_m, bn_v, conv_b,
                                                         scale, bias, L * H);
    pack_W_kernel<<<L * 32, 64, 0, stream>>>(conv_W, Whi, Wlo);

    const float* hin = x;
    for (int l = 0; l < L; ++l) {
        gemm_mfma_kernel<<<(N + 127) / 128, 256, 0, stream>>>(hin,
                                                              Whi + (size_t)l * H * H,
                                                              Wlo + (size_t)l * H * H,
                                                              dis, bufA, N);
        agg_kernel<<<(N + 3) / 4, 256, 0, stream>>>(bufA, row_ptr, sorted_src, dis,
                                                    scale + l * H, bias + l * H, bufB, N);
        hin = bufB;
    }

    pool_kernel<<<(N + 255) / 256, 128, 0, stream>>>(bufB, batch, pooled, N);
    head_kernel<<<NUM_GRAPHS, 128, 0, stream>>>(pooled, cW1, cb1, cW2, cb2,
                                                nW1, nb1, nW2, nb2, (float*)d_out);
}

// Round 4
// 774.359 us; speedup vs baseline: 2.0424x; 1.3226x over previous
//
#include <hip/hip_runtime.h>
#include <hip/hip_fp16.h>
#include <cstdint>
#include <cstddef>

#define NUM_GRAPHS 64
#define HDIM 128
#define NBLK_S 256   // blocks for histogram/scatter passes

typedef __attribute__((ext_vector_type(8))) _Float16 half8v;
typedef __attribute__((ext_vector_type(4))) float float4v;

// ---------------------------------------------------------------------------
// count in-degree (global atomics on 400KB, L2-resident) + per-(block,bucket)
// histogram for the bucket sort. bucket = dst >> shift, NB <= 256.
__global__ __launch_bounds__(256) void count_hist_kernel(const int* __restrict__ dst,
                                                         int* __restrict__ cnt,
                                                         int* __restrict__ hist,
                                                         int E, int chunk, int shift, int NB) {
    __shared__ int lh[256];
    int t = threadIdx.x;
    int b = blockIdx.x;
    lh[t] = 0;
    __syncthreads();
    int beg = b * chunk;
    int end = beg + chunk; if (end > E) end = E;
    for (int i = beg + t; i < end; i += 256) {
        int d = dst[i];
        atomicAdd(&cnt[d], 1);
        atomicAdd(&lh[d >> shift], 1);
    }
    __syncthreads();
    for (int k = t; k < NB; k += 256) hist[k * NBLK_S + b] = lh[k];
}

// --- generic hierarchical scan pieces ---
__global__ __launch_bounds__(256) void scan_partial_kernel(const int* __restrict__ in,
                                                           int* __restrict__ blockSums, int M) {
    __shared__ int s[256];
    int t = threadIdx.x;
    int base = blockIdx.x * 4096 + t * 16;
    int local = 0;
#pragma unroll
    for (int i = 0; i < 16; ++i) {
        int idx = base + i;
        if (idx < M) local += in[idx];
    }
    s[t] = local;
    __syncthreads();
    for (int off = 128; off > 0; off >>= 1) {
        if (t < off) s[t] += s[t + off];
        __syncthreads();
    }
    if (t == 0) blockSums[blockIdx.x] = s[0];
}

__global__ __launch_bounds__(1024) void scan_blocksums_kernel(int* __restrict__ blockSums,
                                                              int* __restrict__ row_ptr_or_null,
                                                              int nb, int E, int N) {
    __shared__ int s[1024];
    int t = threadIdx.x;
    int v = (t < nb) ? blockSums[t] : 0;
    s[t] = v;
    __syncthreads();
    for (int off = 1; off < 1024; off <<= 1) {
        int u = (t >= off) ? s[t - off] : 0;
        __syncthreads();
        s[t] += u;
        __syncthreads();
    }
    if (t < nb) blockSums[t] = s[t] - v;  // exclusive
    if (t == 0 && row_ptr_or_null) row_ptr_or_null[N] = E;
}

// specialized apply for node counts -> row_ptr / fill / dis
__global__ __launch_bounds__(256) void scan_apply_kernel(const int* __restrict__ cnt,
                                                         const int* __restrict__ blockSums,
                                                         int* __restrict__ row_ptr,
                                                         int* __restrict__ fill,
                                                         float* __restrict__ dis, int N) {
    __shared__ int s[256];
    int t = threadIdx.x;
    int base = blockIdx.x * 4096 + t * 16;
    int c[16];
    int local = 0;
#pragma unroll
    for (int i = 0; i < 16; ++i) {
        int idx = base + i;
        c[i] = (idx < N) ? cnt[idx] : 0;
        local += c[i];
    }
    s[t] = local;
    __syncthreads();
    for (int off = 1; off < 256; off <<= 1) {
        int u = (t >= off) ? s[t - off] : 0;
        __syncthreads();
        s[t] += u;
        __syncthreads();
    }
    int pos = blockSums[blockIdx.x] + s[t] - local;
#pragma unroll
    for (int i = 0; i < 16; ++i) {
        int idx = base + i;
        if (idx < N) {
            row_ptr[idx] = pos;
            fill[idx] = pos;
            dis[idx] = rsqrtf((float)c[i] + 1.0f);
            pos += c[i];
        }
    }
}

// generic apply: out[i] = exclusive prefix (in-place safe)
__global__ __launch_bounds__(256) void scan_apply_generic(int* __restrict__ io,
                                                          const int* __restrict__ blockSums, int M) {
    __shared__ int s[256];
    int t = threadIdx.x;
    int base = blockIdx.x * 4096 + t * 16;
    int c[16];
    int local = 0;
#pragma unroll
    for (int i = 0; i < 16; ++i) {
        int idx = base + i;
        c[i] = (idx < M) ? io[idx] : 0;
        local += c[i];
    }
    s[t] = local;
    __syncthreads();
    for (int off = 1; off < 256; off <<= 1) {
        int u = (t >= off) ? s[t - off] : 0;
        __syncthreads();
        s[t] += u;
        __syncthreads();
    }
    int pos = blockSums[blockIdx.x] + s[t] - local;
#pragma unroll
    for (int i = 0; i < 16; ++i) {
        int idx = base + i;
        if (idx < M) {
            io[idx] = pos;
            pos += c[i];
        }
    }
}

// scatter edges into bucket-grouped pair array (runs of ~chunk/NB per bucket)
__global__ __launch_bounds__(256) void scatter_bucket_kernel(const int* __restrict__ src,
                                                             const int* __restrict__ dst,
                                                             const int* __restrict__ hist,
                                                             int2* __restrict__ pairs,
                                                             int E, int chunk, int shift, int NB) {
    __shared__ int base[256];
    int t = threadIdx.x;
    int b = blockIdx.x;
    for (int k = t; k < NB; k += 256) base[k] = hist[k * NBLK_S + b];
    __syncthreads();
    int beg = b * chunk;
    int end = beg + chunk; if (end > E) end = E;
    for (int i = beg + t; i < end; i += 256) {
        int d = dst[i];
        int s = src[i];
        int pos = atomicAdd(&base[d >> shift], 1);
        pairs[pos] = make_int2(s, d);
    }
}

// final CSR fill over bucket-grouped pairs: writes land in ~32KB/bucket windows
__global__ __launch_bounds__(256) void fill_pairs_kernel(const int2* __restrict__ pairs,
                                                         int* __restrict__ fill,
                                                         int* __restrict__ sorted_src, int E) {
    int i = blockIdx.x * 256 + threadIdx.x;
    if (i < E) {
        int2 p = pairs[i];
        int pos = atomicAdd(&fill[p.y], 1);
        sorted_src[pos] = p.x;
    }
}

// ---------------------------------------------------------------------------
// Fold BN(eval)+conv bias into scale/bias per (layer, feature)
__global__ __launch_bounds__(256) void fold_kernel(const float* __restrict__ gamma,
                                                   const float* __restrict__ beta,
                                                   const float* __restrict__ mean,
                                                   const float* __restrict__ var,
                                                   const float* __restrict__ convb,
                                                   float* __restrict__ scale,
                                                   float* __restrict__ bias, int LH) {
    int i = blockIdx.x * 256 + threadIdx.x;
    if (i < LH) {
        float gs = gamma[i] * rsqrtf(var[i] + 1e-5f);
        scale[i] = gs;
        bias[i] = (convb[i] - mean[i]) * gs + beta[i];
    }
}

// x (fp32) -> fp16
__global__ __launch_bounds__(256) void f32_to_f16_kernel(const float* __restrict__ in,
                                                         __half* __restrict__ out, int n2) {
    int stride = gridDim.x * 256;
    for (int i = blockIdx.x * 256 + threadIdx.x; i < n2; i += stride) {
        float2 v = ((const float2*)in)[i];
        ((__half2*)out)[i] = __floats2half2_rn(v.x, v.y);
    }
}

// ---------------------------------------------------------------------------
// Pack W[l] into MFMA B-fragment layout, split f16 hi + f16 lo.
// B[k][n]: n = ntile*16 + (lane&15), k = kchunk*32 + (lane>>4)*8 + j
__global__ __launch_bounds__(64) void pack_W_kernel(const float* __restrict__ W,
                                                    __half* __restrict__ hi,
                                                    __half* __restrict__ lo) {
    int b = blockIdx.x;         // l*32 + ntile*4 + kchunk
    int l = b >> 5;
    int ntile = (b >> 2) & 7;
    int kchunk = b & 3;
    int lane = threadIdx.x;
    int n = ntile * 16 + (lane & 15);
    int kbase = kchunk * 32 + (lane >> 4) * 8;
    size_t ob = ((size_t)b * 64 + lane) * 8;
#pragma unroll
    for (int j = 0; j < 8; ++j) {
        float w = W[(size_t)l * 16384 + (size_t)(kbase + j) * 128 + n];
        __half hb = __float2half_rn(w);
        float rem = w - __half2float(hb);
        hi[ob + j] = hb;
        lo[ob + j] = __float2half_rn(rem);
    }
}

// ---------------------------------------------------------------------------
// MFMA GEMM (f16, split-W): out16[n] = f16( dis[n] * (h[n] @ W) )
// A frag: direct 16B load of fp16 h (exact). B = Whi + Wlo -> 2 MFMAs.
// D: node row = mbase+mt*16+(lane>>4)*4+r, feat = nt*16+(lane&15)
__global__ __launch_bounds__(256) void gemm_mfma_f16(const __half* __restrict__ h,
                                                     const __half* __restrict__ Whi,
                                                     const __half* __restrict__ Wlo,
                                                     const float* __restrict__ dis,
                                                     __half* __restrict__ out, int N) {
    int wave = threadIdx.x >> 6;
    int lane = threadIdx.x & 63;
    int lrow = lane & 15;
    int lk8 = lane >> 4;
    int mbase = blockIdx.x * 128 + wave * 32;

    float4v acc[2][8];
#pragma unroll
    for (int mt = 0; mt < 2; ++mt)
#pragma unroll
        for (int nt = 0; nt < 8; ++nt) {
            acc[mt][nt][0] = 0.f; acc[mt][nt][1] = 0.f;
            acc[mt][nt][2] = 0.f; acc[mt][nt][3] = 0.f;
        }

    const half8v* BH = (const half8v*)Whi;
    const half8v* BL = (const half8v*)Wlo;
    const half8v* H8 = (const half8v*)h;

    for (int kc = 0; kc < 4; ++kc) {
        half8v a[2];
#pragma unroll
        for (int mt = 0; mt < 2; ++mt) {
            int node = mbase + mt * 16 + lrow;
            if (node < N) {
                a[mt] = H8[(size_t)node * 16 + kc * 4 + lk8];
            } else {
#pragma unroll
                for (int j = 0; j < 8; ++j) a[mt][j] = (_Float16)0;
            }
        }
#pragma unroll
        for (int nt = 0; nt < 8; ++nt) {
            half8v bh = BH[(size_t)(nt * 4 + kc) * 64 + lane];
            half8v bl = BL[(size_t)(nt * 4 + kc) * 64 + lane];
#pragma unroll
            for (int mt = 0; mt < 2; ++mt) {
                acc[mt][nt] = __builtin_amdgcn_mfma_f32_16x16x32_f16(a[mt], bh, acc[mt][nt], 0, 0, 0);
                acc[mt][nt] = __builtin_amdgcn_mfma_f32_16x16x32_f16(a[mt], bl, acc[mt][nt], 0, 0, 0);
            }
        }
    }

#pragma unroll
    for (int mt = 0; mt < 2; ++mt) {
#pragma unroll
        for (int r = 0; r < 4; ++r) {
            int node = mbase + mt * 16 + lk8 * 4 + r;
            if (node < N) {
                float dn = dis[node];
#pragma unroll
                for (int nt = 0; nt < 8; ++nt)
                    out[(size_t)node * HDIM + nt * 16 + lrow] = __float2half_rn(acc[mt][nt][r] * dn);
            }
        }
    }
}

// ---------------------------------------------------------------------------
// Aggregate: hout[n] = f16( relu( dis[n]*(sum hwp[src] + hwp[n]) * scale + bias ) )
// One wave per node; lane holds 2 features (half2 = 4B) -> 256B coalesced rows.
__global__ __launch_bounds__(256) void agg_kernel(const __half* __restrict__ hwp,
                                                  const int* __restrict__ row_ptr,
                                                  const int* __restrict__ sorted_src,
                                                  const float* __restrict__ dis,
                                                  const float* __restrict__ scale,
                                                  const float* __restrict__ bias,
                                                  __half* __restrict__ hout, int N) {
    int wave = threadIdx.x >> 6;
    int lane = threadIdx.x & 63;
    int n = blockIdx.x * 4 + wave;
    if (n >= N) return;
    const __half2* hw2 = (const __half2*)hwp;

    float2 acc = __half22float2(hw2[(size_t)n * 64 + lane]);  // self term
    int e0 = row_ptr[n];
    int e1 = row_ptr[n + 1];
    int e = e0;
    for (; e + 3 < e1; e += 4) {
        int s0 = sorted_src[e];
        int s1 = sorted_src[e + 1];
        int s2 = sorted_src[e + 2];
        int s3 = sorted_src[e + 3];
        float2 v0 = __half22float2(hw2[(size_t)s0 * 64 + lane]);
        float2 v1 = __half22float2(hw2[(size_t)s1 * 64 + lane]);
        float2 v2 = __half22float2(hw2[(size_t)s2 * 64 + lane]);
        float2 v3 = __half22float2(hw2[(size_t)s3 * 64 + lane]);
        acc.x += v0.x + v1.x + v2.x + v3.x;
        acc.y += v0.y + v1.y + v2.y + v3.y;
    }
    for (; e < e1; ++e) {
        float2 v0 = __half22float2(hw2[(size_t)sorted_src[e] * 64 + lane]);
        acc.x += v0.x;
        acc.y += v0.y;
    }
    float dn = dis[n];
    int f0 = lane * 2;
    float y0 = fmaxf(dn * acc.x * scale[f0] + bias[f0], 0.f);
    float y1 = fmaxf(dn * acc.y * scale[f0 + 1] + bias[f0 + 1], 0.f);
    ((__half2*)hout)[(size_t)n * 64 + lane] = __floats2half2_rn(y0, y1);
}

// ---------------------------------------------------------------------------
// Global add pool using sortedness of batch (h in fp16, fp32 accum).
__global__ __launch_bounds__(128) void pool_kernel(const __half* __restrict__ h,
                                                   const int* __restrict__ batch,
                                                   float* __restrict__ pooled, int N) {
    int f = threadIdx.x;
    int n0 = blockIdx.x * 256;
    if (n0 >= N) return;
    int nend = n0 + 256; if (nend > N) nend = N;
    float acc = 0.f;
    int g = batch[n0];
    for (int n = n0; n < nend; ++n) {
        int gn = batch[n];
        if (gn != g) {
            atomicAdd(&pooled[g * HDIM + f], acc);
            acc = 0.f;
            g = gn;
        }
        acc += __half2float(h[(size_t)n * HDIM + f]);
    }
    atomicAdd(&pooled[g * HDIM + f], acc);
}

// ---------------------------------------------------------------------------
// Heads: one block per graph.
__global__ __launch_bounds__(128) void head_kernel(const float* __restrict__ pooled,
                                                   const float* __restrict__ cW1, const float* __restrict__ cb1,
                                                   const float* __restrict__ cW2, const float* __restrict__ cb2,
                                                   const float* __restrict__ nW1, const float* __restrict__ nb1,
                                                   const float* __restrict__ nW2, const float* __restrict__ nb2,
                                                   float* __restrict__ out) {
    __shared__ float p[128];
    __shared__ float hid[128];
    int g = blockIdx.x, t = threadIdx.x;
    p[t] = pooled[g * HDIM + t];
    __syncthreads();

    float a = cb1[t];
    for (int k = 0; k < 128; ++k) a += p[k] * cW1[k * 128 + t];
    hid[t] = fmaxf(a, 0.f);
    __syncthreads();
    if (t < 16) {
        float acc = cb2[t];
        for (int j = 0; j < 128; ++j) acc += hid[j] * cW2[j * 16 + t];
        out[g * 16 + t] = acc;
    }
    __syncthreads();

    float b = nb1[t];
    for (int k = 0; k < 128; ++k) b += p[k] * nW1[k * 128 + t];
    hid[t] = fmaxf(b, 0.f);
    __syncthreads();
    if (t == 0) {
        float acc = nb2[0];
        for (int j = 0; j < 128; ++j) acc += hid[j] * nW2[j];
        out[NUM_GRAPHS * 16 + g] = 1.f / (1.f + expf(-acc));
    }
}

// ---------------------------------------------------------------------------
extern "C" void kernel_launch(void* const* d_in, const int* in_sizes, int n_in,
                              void* d_out, int out_size, void* d_ws, size_t ws_size,
                              hipStream_t stream) {
    const float* x       = (const float*)d_in[0];
    const int*   ei      = (const int*)d_in[1];
    const int*   batch   = (const int*)d_in[2];
    const float* conv_W  = (const float*)d_in[3];
    const float* conv_b  = (const float*)d_in[4];
    const float* bn_g    = (const float*)d_in[5];
    const float* bn_b    = (const float*)d_in[6];
    const float* bn_m    = (const float*)d_in[7];
    const float* bn_v    = (const float*)d_in[8];
    const float* cW1     = (const float*)d_in[9];
    const float* cb1     = (const float*)d_in[10];
    const float* cW2     = (const float*)d_in[11];
    const float* cb2     = (const float*)d_in[12];
    const float* nW1     = (const float*)d_in[13];
    const float* nb1     = (const float*)d_in[14];
    const float* nW2     = (const float*)d_in[15];
    const float* nb2     = (const float*)d_in[16];

    const int N = in_sizes[2];
    const int E = in_sizes[1] / 2;
    const int L = in_sizes[3] / (128 * 128);
    const int H = HDIM;

    const int* src = ei;
    const int* dst = ei + E;

    // bucket geometry: NB buckets of 2^shift nodes, NB <= 256
    int shift = 9;
    while ((((N - 1) >> shift) + 1) > 256) ++shift;
    const int NB = ((N - 1) >> shift) + 1;
    const int M = NB * NBLK_S;
    const int chunk = (E + NBLK_S - 1) / NBLK_S;

    char* w = (char*)d_ws;
    size_t o = 0;
    auto alloc = [&](size_t bytes) -> void* {
        void* p = w + o;
        o = (o + bytes + 255) & ~(size_t)255;
        return p;
    };
    int nscanN = (N + 4095) / 4096;
    int nscanM = (M + 4095) / 4096;
    int nscanMax = nscanN > nscanM ? nscanN : nscanM;

    int*    cnt        = (int*)alloc((size_t)N * 4);
    int*    fill       = (int*)alloc((size_t)N * 4);
    int*    row_ptr    = (int*)alloc((size_t)(N + 1) * 4);
    float*  dis        = (float*)alloc((size_t)N * 4);
    float*  scale      = (float*)alloc((size_t)L * H * 4);
    float*  bias       = (float*)alloc((size_t)L * H * 4);
    int*    blockSums  = (int*)alloc((size_t)nscanMax * 4);
    int*    hist       = (int*)alloc((size_t)M * 4);
    int2*   pairs      = (int2*)alloc((size_t)E * 8);
    int*    sorted_src = (int*)alloc((size_t)E * 4);
    __half* Whi        = (__half*)alloc((size_t)L * H * H * 2);
    __half* Wlo        = (__half*)alloc((size_t)L * H * H * 2);
    __half* x16        = (__half*)alloc((size_t)N * H * 2);
    __half* bufA       = (__half*)alloc((size_t)N * H * 2);  // hw' table
    __half* bufB       = (__half*)alloc((size_t)N * H * 2);  // h
    float*  pooled     = (float*)alloc((size_t)NUM_GRAPHS * H * 4);

    hipMemsetAsync(cnt, 0, (size_t)N * 4, stream);
    hipMemsetAsync(pooled, 0, (size_t)NUM_GRAPHS * H * 4, stream);

    // CSR degree + bucket histograms
    count_hist_kernel<<<NBLK_S, 256, 0, stream>>>(dst, cnt, hist, E, chunk, shift, NB);
    // row_ptr / fill / dis from per-node counts
    scan_partial_kernel<<<nscanN, 256, 0, stream>>>(cnt, blockSums, N);
    scan_blocksums_kernel<<<1, 1024, 0, stream>>>(blockSums, row_ptr, nscanN, E, N);
    scan_apply_kernel<<<nscanN, 256, 0, stream>>>(cnt, blockSums, row_ptr, fill, dis, N);
    // bucket offsets
    scan_partial_kernel<<<nscanM, 256, 0, stream>>>(hist, blockSums, M);
    scan_blocksums_kernel<<<1, 1024, 0, stream>>>(blockSums, nullptr, nscanM, 0, 0);
    scan_apply_generic<<<nscanM, 256, 0, stream>>>(hist, blockSums, M);
    // bucket-grouped pairs, then locality-friendly CSR fill
    scatter_bucket_kernel<<<NBLK_S, 256, 0, stream>>>(src, dst, hist, pairs, E, chunk, shift, NB);
    fill_pairs_kernel<<<(E + 255) / 256, 256, 0, stream>>>(pairs, fill, sorted_src, E);

    fold_kernel<<<(L * H + 255) / 256, 256, 0, stream>>>(bn_g, bn_b, bn_m, bn_v, conv_b,
                                                         scale, bias, L * H);
    pack_W_kernel<<<L * 32, 64, 0, stream>>>(conv_W, Whi, Wlo);
    f32_to_f16_kernel<<<2048, 256, 0, stream>>>(x, x16, N * H / 2);

    const __half* hin = x16;
    for (int l = 0; l < L; ++l) {
        gemm_mfma_f16<<<(N + 127) / 128, 256, 0, stream>>>(hin,
                                                           Whi + (size_t)l * H * H,
                                                           Wlo + (size_t)l * H * H,
                                                           dis, bufA, N);
        agg_kernel<<<(N + 3) / 4, 256, 0, stream>>>(bufA, row_ptr, sorted_src, dis,
                                                    scale + l * H, bias + l * H, bufB, N);
        hin = bufB;
    }

    pool_kernel<<<(N + 255) / 256, 128, 0, stream>>>(bufB, batch, pooled, N);
    head_kernel<<<NUM_GRAPHS, 128, 0, stream>>>(pooled, cW1, cb1, cW2, cb2,
                                                nW1, nb1, nW2, nb2, (float*)d_out);
}

// Round 5
// 745.704 us; speedup vs baseline: 2.1208x; 1.0384x over previous
//
#include <hip/hip_runtime.h>
#include <hip/hip_fp16.h>
#include <cstdint>
#include <cstddef>

#define NUM_GRAPHS 64
#define HDIM 128
#define NBLK_S 256   // blocks for histogram/scatter passes

typedef __attribute__((ext_vector_type(8))) _Float16 half8v;
typedef __attribute__((ext_vector_type(4))) float float4v;

// ---------------------------------------------------------------------------
// count in-degree + per-(block,bucket) histogram for the bucket sort.
__global__ __launch_bounds__(256) void count_hist_kernel(const int* __restrict__ dst,
                                                         int* __restrict__ cnt,
                                                         int* __restrict__ hist,
                                                         int E, int chunk, int shift, int NB) {
    __shared__ int lh[256];
    int t = threadIdx.x;
    int b = blockIdx.x;
    lh[t] = 0;
    __syncthreads();
    int beg = b * chunk;
    int end = beg + chunk; if (end > E) end = E;
    for (int i = beg + t; i < end; i += 256) {
        int d = dst[i];
        atomicAdd(&cnt[d], 1);
        atomicAdd(&lh[d >> shift], 1);
    }
    __syncthreads();
    for (int k = t; k < NB; k += 256) hist[k * NBLK_S + b] = lh[k];
}

// --- hierarchical scan pieces ---
__global__ __launch_bounds__(256) void scan_partial_kernel(const int* __restrict__ in,
                                                           int* __restrict__ blockSums, int M) {
    __shared__ int s[256];
    int t = threadIdx.x;
    int base = blockIdx.x * 4096 + t * 16;
    int local = 0;
#pragma unroll
    for (int i = 0; i < 16; ++i) {
        int idx = base + i;
        if (idx < M) local += in[idx];
    }
    s[t] = local;
    __syncthreads();
    for (int off = 128; off > 0; off >>= 1) {
        if (t < off) s[t] += s[t + off];
        __syncthreads();
    }
    if (t == 0) blockSums[blockIdx.x] = s[0];
}

__global__ __launch_bounds__(1024) void scan_blocksums_kernel(int* __restrict__ blockSums,
                                                              int* __restrict__ row_ptr_or_null,
                                                              int nb, int E, int N) {
    __shared__ int s[1024];
    int t = threadIdx.x;
    int v = (t < nb) ? blockSums[t] : 0;
    s[t] = v;
    __syncthreads();
    for (int off = 1; off < 1024; off <<= 1) {
        int u = (t >= off) ? s[t - off] : 0;
        __syncthreads();
        s[t] += u;
        __syncthreads();
    }
    if (t < nb) blockSums[t] = s[t] - v;  // exclusive
    if (t == 0 && row_ptr_or_null) row_ptr_or_null[N] = E;
}

__global__ __launch_bounds__(256) void scan_apply_kernel(const int* __restrict__ cnt,
                                                         const int* __restrict__ blockSums,
                                                         int* __restrict__ row_ptr,
                                                         int* __restrict__ fill,
                                                         float* __restrict__ dis, int N) {
    __shared__ int s[256];
    int t = threadIdx.x;
    int base = blockIdx.x * 4096 + t * 16;
    int c[16];
    int local = 0;
#pragma unroll
    for (int i = 0; i < 16; ++i) {
        int idx = base + i;
        c[i] = (idx < N) ? cnt[idx] : 0;
        local += c[i];
    }
    s[t] = local;
    __syncthreads();
    for (int off = 1; off < 256; off <<= 1) {
        int u = (t >= off) ? s[t - off] : 0;
        __syncthreads();
        s[t] += u;
        __syncthreads();
    }
    int pos = blockSums[blockIdx.x] + s[t] - local;
#pragma unroll
    for (int i = 0; i < 16; ++i) {
        int idx = base + i;
        if (idx < N) {
            row_ptr[idx] = pos;
            fill[idx] = pos;
            dis[idx] = rsqrtf((float)c[i] + 1.0f);
            pos += c[i];
        }
    }
}

__global__ __launch_bounds__(256) void scan_apply_generic(int* __restrict__ io,
                                                          const int* __restrict__ blockSums, int M) {
    __shared__ int s[256];
    int t = threadIdx.x;
    int base = blockIdx.x * 4096 + t * 16;
    int c[16];
    int local = 0;
#pragma unroll
    for (int i = 0; i < 16; ++i) {
        int idx = base + i;
        c[i] = (idx < M) ? io[idx] : 0;
        local += c[i];
    }
    s[t] = local;
    __syncthreads();
    for (int off = 1; off < 256; off <<= 1) {
        int u = (t >= off) ? s[t - off] : 0;
        __syncthreads();
        s[t] += u;
        __syncthreads();
    }
    int pos = blockSums[blockIdx.x] + s[t] - local;
#pragma unroll
    for (int i = 0; i < 16; ++i) {
        int idx = base + i;
        if (idx < M) {
            io[idx] = pos;
            pos += c[i];
        }
    }
}

// scatter edges into bucket-grouped pair array
__global__ __launch_bounds__(256) void scatter_bucket_kernel(const int* __restrict__ src,
                                                             const int* __restrict__ dst,
                                                             const int* __restrict__ hist,
                                                             int2* __restrict__ pairs,
                                                             int E, int chunk, int shift, int NB) {
    __shared__ int base[256];
    int t = threadIdx.x;
    int b = blockIdx.x;
    for (int k = t; k < NB; k += 256) base[k] = hist[k * NBLK_S + b];
    __syncthreads();
    int beg = b * chunk;
    int end = beg + chunk; if (end > E) end = E;
    for (int i = beg + t; i < end; i += 256) {
        int d = dst[i];
        int s = src[i];
        int pos = atomicAdd(&base[d >> shift], 1);
        pairs[pos] = make_int2(s, d);
    }
}

// final CSR fill over bucket-grouped pairs
__global__ __launch_bounds__(256) void fill_pairs_kernel(const int2* __restrict__ pairs,
                                                         int* __restrict__ fill,
                                                         int* __restrict__ sorted_src, int E) {
    int i = blockIdx.x * 256 + threadIdx.x;
    if (i < E) {
        int2 p = pairs[i];
        int pos = atomicAdd(&fill[p.y], 1);
        sorted_src[pos] = p.x;
    }
}

// ---------------------------------------------------------------------------
// Fold BN(eval)+conv bias into scale/bias per (layer, feature)
__global__ __launch_bounds__(256) void fold_kernel(const float* __restrict__ gamma,
                                                   const float* __restrict__ beta,
                                                   const float* __restrict__ mean,
                                                   const float* __restrict__ var,
                                                   const float* __restrict__ convb,
                                                   float* __restrict__ scale,
                                                   float* __restrict__ bias, int LH) {
    int i = blockIdx.x * 256 + threadIdx.x;
    if (i < LH) {
        float gs = gamma[i] * rsqrtf(var[i] + 1e-5f);
        scale[i] = gs;
        bias[i] = (convb[i] - mean[i]) * gs + beta[i];
    }
}

// ---------------------------------------------------------------------------
// Pack W[l] into MFMA B-fragment layout, split f16 hi + f16 lo.
__global__ __launch_bounds__(64) void pack_W_kernel(const float* __restrict__ W,
                                                    __half* __restrict__ hi,
                                                    __half* __restrict__ lo) {
    int b = blockIdx.x;         // l*32 + ntile*4 + kchunk
    int l = b >> 5;
    int ntile = (b >> 2) & 7;
    int kchunk = b & 3;
    int lane = threadIdx.x;
    int n = ntile * 16 + (lane & 15);
    int kbase = kchunk * 32 + (lane >> 4) * 8;
    size_t ob = ((size_t)b * 64 + lane) * 8;
#pragma unroll
    for (int j = 0; j < 8; ++j) {
        float w = W[(size_t)l * 16384 + (size_t)(kbase + j) * 128 + n];
        __half hb = __float2half_rn(w);
        float rem = w - __half2float(hb);
        hi[ob + j] = hb;
        lo[ob + j] = __float2half_rn(rem);
    }
}

// ---------------------------------------------------------------------------
// MFMA GEMM (f16, split-W): out16[n] = f16( dis[n] * (h[n] @ W) )
// h16 used when h32==nullptr; layer 0 reads fp32 x directly (RNE to fp16).
__global__ __launch_bounds__(256) void gemm_mfma_f16(const __half* __restrict__ h16,
                                                     const float* __restrict__ h32,
                                                     const __half* __restrict__ Whi,
                                                     const __half* __restrict__ Wlo,
                                                     const float* __restrict__ dis,
                                                     __half* __restrict__ out, int N) {
    int wave = threadIdx.x >> 6;
    int lane = threadIdx.x & 63;
    int lrow = lane & 15;
    int lk8 = lane >> 4;
    int mbase = blockIdx.x * 128 + wave * 32;

    float4v acc[2][8];
#pragma unroll
    for (int mt = 0; mt < 2; ++mt)
#pragma unroll
        for (int nt = 0; nt < 8; ++nt) {
            acc[mt][nt][0] = 0.f; acc[mt][nt][1] = 0.f;
            acc[mt][nt][2] = 0.f; acc[mt][nt][3] = 0.f;
        }

    const half8v* BH = (const half8v*)Whi;
    const half8v* BL = (const half8v*)Wlo;
    const half8v* H8 = (const half8v*)h16;

    for (int kc = 0; kc < 4; ++kc) {
        half8v a[2];
#pragma unroll
        for (int mt = 0; mt < 2; ++mt) {
            int node = mbase + mt * 16 + lrow;
            if (node < N) {
                if (h32) {
                    const float4* hp = (const float4*)&h32[(size_t)node * HDIM + kc * 32 + lk8 * 8];
                    float4 f0 = hp[0], f1 = hp[1];
                    a[mt][0] = (_Float16)f0.x; a[mt][1] = (_Float16)f0.y;
                    a[mt][2] = (_Float16)f0.z; a[mt][3] = (_Float16)f0.w;
                    a[mt][4] = (_Float16)f1.x; a[mt][5] = (_Float16)f1.y;
                    a[mt][6] = (_Float16)f1.z; a[mt][7] = (_Float16)f1.w;
                } else {
                    a[mt] = H8[(size_t)node * 16 + kc * 4 + lk8];
                }
            } else {
#pragma unroll
                for (int j = 0; j < 8; ++j) a[mt][j] = (_Float16)0;
            }
        }
#pragma unroll
        for (int nt = 0; nt < 8; ++nt) {
            half8v bh = BH[(size_t)(nt * 4 + kc) * 64 + lane];
            half8v bl = BL[(size_t)(nt * 4 + kc) * 64 + lane];
#pragma unroll
            for (int mt = 0; mt < 2; ++mt) {
                acc[mt][nt] = __builtin_amdgcn_mfma_f32_16x16x32_f16(a[mt], bh, acc[mt][nt], 0, 0, 0);
                acc[mt][nt] = __builtin_amdgcn_mfma_f32_16x16x32_f16(a[mt], bl, acc[mt][nt], 0, 0, 0);
            }
        }
    }

#pragma unroll
    for (int mt = 0; mt < 2; ++mt) {
#pragma unroll
        for (int r = 0; r < 4; ++r) {
            int node = mbase + mt * 16 + lk8 * 4 + r;
            if (node < N) {
                float dn = dis[node];
#pragma unroll
                for (int nt = 0; nt < 8; ++nt)
                    out[(size_t)node * HDIM + nt * 16 + lrow] = __float2half_rn(acc[mt][nt][r] * dn);
            }
        }
    }
}

// ---------------------------------------------------------------------------
// Aggregate v2: one wave per node; lane holds 4 feats (8B). Wave's two halves
// gather TWO edges per load instruction (even edges -> lanes 0-31, odd ->
// lanes 32-63); combined at the end via shfl_xor(32). Unroll 4 pairs.
__device__ inline void acc_add8(float4& a, uint2 v) {
    float2 f0 = __half22float2(*(__half2*)&v.x);
    float2 f1 = __half22float2(*(__half2*)&v.y);
    a.x += f0.x; a.y += f0.y; a.z += f1.x; a.w += f1.y;
}

__global__ __launch_bounds__(256) void agg_kernel(const __half* __restrict__ hwp,
                                                  const int* __restrict__ row_ptr,
                                                  const int* __restrict__ ss,
                                                  const float* __restrict__ dis,
                                                  const float* __restrict__ scale,
                                                  const float* __restrict__ bias,
                                                  __half* __restrict__ hout, int N) {
    int wave = threadIdx.x >> 6;
    int lane = threadIdx.x & 63;
    int n = blockIdx.x * 4 + wave;
    if (n >= N) return;
    int hid = lane >> 5;     // which half of the wave
    int l32 = lane & 31;
    const uint2* rows = (const uint2*)hwp;  // row = 32 x uint2 (8B per lane)

    float4 acc0 = make_float4(0.f, 0.f, 0.f, 0.f);
    float4 acc1 = make_float4(0.f, 0.f, 0.f, 0.f);

    // self term: half 0 only
    if (hid == 0) {
        uint2 sv = rows[(size_t)n * 32 + l32];
        acc_add8(acc0, sv);
    }

    int e0 = row_ptr[n];
    int e1 = row_ptr[n + 1];
    int e = e0;
    for (; e + 7 < e1; e += 8) {
        int sA = ss[e], sB = ss[e + 1], sC = ss[e + 2], sD = ss[e + 3];
        int sE = ss[e + 4], sF = ss[e + 5], sG = ss[e + 6], sH = ss[e + 7];
        int q0 = hid ? sB : sA;
        int q1 = hid ? sD : sC;
        int q2 = hid ? sF : sE;
        int q3 = hid ? sH : sG;
        uint2 v0 = rows[(size_t)q0 * 32 + l32];
        uint2 v1 = rows[(size_t)q1 * 32 + l32];
        uint2 v2 = rows[(size_t)q2 * 32 + l32];
        uint2 v3 = rows[(size_t)q3 * 32 + l32];
        acc_add8(acc0, v0);
        acc_add8(acc1, v1);
        acc_add8(acc0, v2);
        acc_add8(acc1, v3);
    }
    for (; e + 1 < e1; e += 2) {
        int sA = ss[e], sB = ss[e + 1];
        int q0 = hid ? sB : sA;
        uint2 v0 = rows[(size_t)q0 * 32 + l32];
        acc_add8(acc0, v0);
    }
    if (e < e1) {
        if (hid == 0) {
            int sA = ss[e];
            uint2 v0 = rows[(size_t)sA * 32 + l32];
            acc_add8(acc1, v0);
        }
    }
    acc0.x += acc1.x; acc0.y += acc1.y; acc0.z += acc1.z; acc0.w += acc1.w;

    // combine the two halves
    acc0.x += __shfl_xor(acc0.x, 32);
    acc0.y += __shfl_xor(acc0.y, 32);
    acc0.z += __shfl_xor(acc0.z, 32);
    acc0.w += __shfl_xor(acc0.w, 32);

    if (hid == 0) {
        float dn = dis[n];
        int f0 = l32 * 4;
        float4 sc = *(const float4*)&scale[f0];
        float4 bs = *(const float4*)&bias[f0];
        float y0 = fmaxf(dn * acc0.x * sc.x + bs.x, 0.f);
        float y1 = fmaxf(dn * acc0.y * sc.y + bs.y, 0.f);
        float y2 = fmaxf(dn * acc0.z * sc.z + bs.z, 0.f);
        float y3 = fmaxf(dn * acc0.w * sc.w + bs.w, 0.f);
        __half2 o0 = __floats2half2_rn(y0, y1);
        __half2 o1 = __floats2half2_rn(y2, y3);
        uint2 ov;
        ov.x = *(unsigned*)&o0;
        ov.y = *(unsigned*)&o1;
        ((uint2*)hout)[(size_t)n * 32 + l32] = ov;
    }
}

// ---------------------------------------------------------------------------
// Global add pool using sortedness of batch (h in fp16, fp32 accum).
__global__ __launch_bounds__(128) void pool_kernel(const __half* __restrict__ h,
                                                   const int* __restrict__ batch,
                                                   float* __restrict__ pooled, int N) {
    int f = threadIdx.x;
    int n0 = blockIdx.x * 256;
    if (n0 >= N) return;
    int nend = n0 + 256; if (nend > N) nend = N;
    float acc = 0.f;
    int g = batch[n0];
    for (int n = n0; n < nend; ++n) {
        int gn = batch[n];
        if (gn != g) {
            atomicAdd(&pooled[g * HDIM + f], acc);
            acc = 0.f;
            g = gn;
        }
        acc += __half2float(h[(size_t)n * HDIM + f]);
    }
    atomicAdd(&pooled[g * HDIM + f], acc);
}

// ---------------------------------------------------------------------------
// Heads: one block per graph.
__global__ __launch_bounds__(128) void head_kernel(const float* __restrict__ pooled,
                                                   const float* __restrict__ cW1, const float* __restrict__ cb1,
                                                   const float* __restrict__ cW2, const float* __restrict__ cb2,
                                                   const float* __restrict__ nW1, const float* __restrict__ nb1,
                                                   const float* __restrict__ nW2, const float* __restrict__ nb2,
                                                   float* __restrict__ out) {
    __shared__ float p[128];
    __shared__ float hid[128];
    int g = blockIdx.x, t = threadIdx.x;
    p[t] = pooled[g * HDIM + t];
    __syncthreads();

    float a = cb1[t];
    for (int k = 0; k < 128; ++k) a += p[k] * cW1[k * 128 + t];
    hid[t] = fmaxf(a, 0.f);
    __syncthreads();
    if (t < 16) {
        float acc = cb2[t];
        for (int j = 0; j < 128; ++j) acc += hid[j] * cW2[j * 16 + t];
        out[g * 16 + t] = acc;
    }
    __syncthreads();

    float b = nb1[t];
    for (int k = 0; k < 128; ++k) b += p[k] * nW1[k * 128 + t];
    hid[t] = fmaxf(b, 0.f);
    __syncthreads();
    if (t == 0) {
        float acc = nb2[0];
        for (int j = 0; j < 128; ++j) acc += hid[j] * nW2[j];
        out[NUM_GRAPHS * 16 + g] = 1.f / (1.f + expf(-acc));
    }
}

// ---------------------------------------------------------------------------
extern "C" void kernel_launch(void* const* d_in, const int* in_sizes, int n_in,
                              void* d_out, int out_size, void* d_ws, size_t ws_size,
                              hipStream_t stream) {
    const float* x       = (const float*)d_in[0];
    const int*   ei      = (const int*)d_in[1];
    const int*   batch   = (const int*)d_in[2];
    const float* conv_W  = (const float*)d_in[3];
    const float* conv_b  = (const float*)d_in[4];
    const float* bn_g    = (const float*)d_in[5];
    const float* bn_b    = (const float*)d_in[6];
    const float* bn_m    = (const float*)d_in[7];
    const float* bn_v    = (const float*)d_in[8];
    const float* cW1     = (const float*)d_in[9];
    const float* cb1     = (const float*)d_in[10];
    const float* cW2     = (const float*)d_in[11];
    const float* cb2     = (const float*)d_in[12];
    const float* nW1     = (const float*)d_in[13];
    const float* nb1     = (const float*)d_in[14];
    const float* nW2     = (const float*)d_in[15];
    const float* nb2     = (const float*)d_in[16];

    const int N = in_sizes[2];
    const int E = in_sizes[1] / 2;
    const int L = in_sizes[3] / (128 * 128);
    const int H = HDIM;

    const int* src = ei;
    const int* dst = ei + E;

    int shift = 9;
    while ((((N - 1) >> shift) + 1) > 256) ++shift;
    const int NB = ((N - 1) >> shift) + 1;
    const int M = NB * NBLK_S;
    const int chunk = (E + NBLK_S - 1) / NBLK_S;

    char* w = (char*)d_ws;
    size_t o = 0;
    auto alloc = [&](size_t bytes) -> void* {
        void* p = w + o;
        o = (o + bytes + 255) & ~(size_t)255;
        return p;
    };
    int nscanN = (N + 4095) / 4096;
    int nscanM = (M + 4095) / 4096;
    int nscanMax = nscanN > nscanM ? nscanN : nscanM;

    int*    cnt        = (int*)alloc((size_t)N * 4);
    int*    fill       = (int*)alloc((size_t)N * 4);
    int*    row_ptr    = (int*)alloc((size_t)(N + 1) * 4);
    float*  dis        = (float*)alloc((size_t)N * 4);
    float*  scale      = (float*)alloc((size_t)L * H * 4);
    float*  bias       = (float*)alloc((size_t)L * H * 4);
    int*    blockSums  = (int*)alloc((size_t)nscanMax * 4);
    int*    hist       = (int*)alloc((size_t)M * 4);
    int2*   pairs      = (int2*)alloc((size_t)E * 8);
    int*    sorted_src = (int*)alloc((size_t)E * 4);
    __half* Whi        = (__half*)alloc((size_t)L * H * H * 2);
    __half* Wlo        = (__half*)alloc((size_t)L * H * H * 2);
    __half* bufA       = (__half*)alloc((size_t)N * H * 2);  // hw' table
    __half* bufB       = (__half*)alloc((size_t)N * H * 2);  // h
    float*  pooled     = (float*)alloc((size_t)NUM_GRAPHS * H * 4);

    hipMemsetAsync(cnt, 0, (size_t)N * 4, stream);
    hipMemsetAsync(pooled, 0, (size_t)NUM_GRAPHS * H * 4, stream);

    count_hist_kernel<<<NBLK_S, 256, 0, stream>>>(dst, cnt, hist, E, chunk, shift, NB);
    scan_partial_kernel<<<nscanN, 256, 0, stream>>>(cnt, blockSums, N);
    scan_blocksums_kernel<<<1, 1024, 0, stream>>>(blockSums, row_ptr, nscanN, E, N);
    scan_apply_kernel<<<nscanN, 256, 0, stream>>>(cnt, blockSums, row_ptr, fill, dis, N);
    scan_partial_kernel<<<nscanM, 256, 0, stream>>>(hist, blockSums, M);
    scan_blocksums_kernel<<<1, 1024, 0, stream>>>(blockSums, nullptr, nscanM, 0, 0);
    scan_apply_generic<<<nscanM, 256, 0, stream>>>(hist, blockSums, M);
    scatter_bucket_kernel<<<NBLK_S, 256, 0, stream>>>(src, dst, hist, pairs, E, chunk, shift, NB);
    fill_pairs_kernel<<<(E + 255) / 256, 256, 0, stream>>>(pairs, fill, sorted_src, E);

    fold_kernel<<<(L * H + 255) / 256, 256, 0, stream>>>(bn_g, bn_b, bn_m, bn_v, conv_b,
                                                         scale, bias, L * H);
    pack_W_kernel<<<L * 32, 64, 0, stream>>>(conv_W, Whi, Wlo);

    const __half* hin = nullptr;  // layer 0 reads x (fp32) directly
    for (int l = 0; l < L; ++l) {
        gemm_mfma_f16<<<(N + 127) / 128, 256, 0, stream>>>(hin, l == 0 ? x : nullptr,
                                                           Whi + (size_t)l * H * H,
                                                           Wlo + (size_t)l * H * H,
                                                           dis, bufA, N);
        agg_kernel<<<(N + 3) / 4, 256, 0, stream>>>(bufA, row_ptr, sorted_src, dis,
                                                    scale + l * H, bias + l * H, bufB, N);
        hin = bufB;
    }

    pool_kernel<<<(N + 255) / 256, 128, 0, stream>>>(bufB, batch, pooled, N);
    head_kernel<<<NUM_GRAPHS, 128, 0, stream>>>(pooled, cW1, cb1, cW2, cb2,
                                                nW1, nb1, nW2, nb2, (float*)d_out);
}

// Round 7
// 697.031 us; speedup vs baseline: 2.2689x; 1.0698x over previous
//
#include <hip/hip_runtime.h>
#include <hip/hip_fp16.h>
#include <cstdint>
#include <cstddef>

#define NUM_GRAPHS 64
#define HDIM 128
#define NBLK_S 256   // blocks for histogram/scatter passes

typedef __attribute__((ext_vector_type(8))) _Float16 half8v;
typedef __attribute__((ext_vector_type(4))) float float4v;

// ---------------------------------------------------------------------------
// count in-degree + per-(block,bucket) histogram for the bucket sort.
__global__ __launch_bounds__(256) void count_hist_kernel(const int* __restrict__ dst,
                                                         int* __restrict__ cnt,
                                                         int* __restrict__ hist,
                                                         int E, int chunk, int shift, int NB) {
    __shared__ int lh[256];
    int t = threadIdx.x;
    int b = blockIdx.x;
    lh[t] = 0;
    __syncthreads();
    int beg = b * chunk;
    int end = beg + chunk; if (end > E) end = E;
    for (int i = beg + t; i < end; i += 256) {
        int d = dst[i];
        atomicAdd(&cnt[d], 1);
        atomicAdd(&lh[d >> shift], 1);
    }
    __syncthreads();
    for (int k = t; k < NB; k += 256) hist[k * NBLK_S + b] = lh[k];
}

// --- hierarchical scan pieces ---
__global__ __launch_bounds__(256) void scan_partial_kernel(const int* __restrict__ in,
                                                           int* __restrict__ blockSums, int M) {
    __shared__ int s[256];
    int t = threadIdx.x;
    int base = blockIdx.x * 4096 + t * 16;
    int local = 0;
#pragma unroll
    for (int i = 0; i < 16; ++i) {
        int idx = base + i;
        if (idx < M) local += in[idx];
    }
    s[t] = local;
    __syncthreads();
    for (int off = 128; off > 0; off >>= 1) {
        if (t < off) s[t] += s[t + off];
        __syncthreads();
    }
    if (t == 0) blockSums[blockIdx.x] = s[0];
}

__global__ __launch_bounds__(1024) void scan_blocksums_kernel(int* __restrict__ blockSums,
                                                              int* __restrict__ row_ptr_or_null,
                                                              int nb, int E, int N) {
    __shared__ int s[1024];
    int t = threadIdx.x;
    int v = (t < nb) ? blockSums[t] : 0;
    s[t] = v;
    __syncthreads();
    for (int off = 1; off < 1024; off <<= 1) {
        int u = (t >= off) ? s[t - off] : 0;
        __syncthreads();
        s[t] += u;
        __syncthreads();
    }
    if (t < nb) blockSums[t] = s[t] - v;  // exclusive
    if (t == 0 && row_ptr_or_null) row_ptr_or_null[N] = E;
}

__global__ __launch_bounds__(256) void scan_apply_kernel(const int* __restrict__ cnt,
                                                         const int* __restrict__ blockSums,
                                                         int* __restrict__ row_ptr,
                                                         int* __restrict__ fill,
                                                         float* __restrict__ dis, int N) {
    __shared__ int s[256];
    int t = threadIdx.x;
    int base = blockIdx.x * 4096 + t * 16;
    int c[16];
    int local = 0;
#pragma unroll
    for (int i = 0; i < 16; ++i) {
        int idx = base + i;
        c[i] = (idx < N) ? cnt[idx] : 0;
        local += c[i];
    }
    s[t] = local;
    __syncthreads();
    for (int off = 1; off < 256; off <<= 1) {
        int u = (t >= off) ? s[t - off] : 0;
        __syncthreads();
        s[t] += u;
        __syncthreads();
    }
    int pos = blockSums[blockIdx.x] + s[t] - local;
#pragma unroll
    for (int i = 0; i < 16; ++i) {
        int idx = base + i;
        if (idx < N) {
            row_ptr[idx] = pos;
            fill[idx] = pos;
            dis[idx] = rsqrtf((float)c[i] + 1.0f);
            pos += c[i];
        }
    }
}

__global__ __launch_bounds__(256) void scan_apply_generic(int* __restrict__ io,
                                                          const int* __restrict__ blockSums, int M) {
    __shared__ int s[256];
    int t = threadIdx.x;
    int base = blockIdx.x * 4096 + t * 16;
    int c[16];
    int local = 0;
#pragma unroll
    for (int i = 0; i < 16; ++i) {
        int idx = base + i;
        c[i] = (idx < M) ? io[idx] : 0;
        local += c[i];
    }
    s[t] = local;
    __syncthreads();
    for (int off = 1; off < 256; off <<= 1) {
        int u = (t >= off) ? s[t - off] : 0;
        __syncthreads();
        s[t] += u;
        __syncthreads();
    }
    int pos = blockSums[blockIdx.x] + s[t] - local;
#pragma unroll
    for (int i = 0; i < 16; ++i) {
        int idx = base + i;
        if (idx < M) {
            io[idx] = pos;
            pos += c[i];
        }
    }
}

// scatter edges into bucket-grouped pair array
__global__ __launch_bounds__(256) void scatter_bucket_kernel(const int* __restrict__ src,
                                                             const int* __restrict__ dst,
                                                             const int* __restrict__ hist,
                                                             int2* __restrict__ pairs,
                                                             int E, int chunk, int shift, int NB) {
    __shared__ int base[256];
    int t = threadIdx.x;
    int b = blockIdx.x;
    for (int k = t; k < NB; k += 256) base[k] = hist[k * NBLK_S + b];
    __syncthreads();
    int beg = b * chunk;
    int end = beg + chunk; if (end > E) end = E;
    for (int i = beg + t; i < end; i += 256) {
        int d = dst[i];
        int s = src[i];
        int pos = atomicAdd(&base[d >> shift], 1);
        pairs[pos] = make_int2(s, d);
    }
}

// final CSR fill over bucket-grouped pairs
__global__ __launch_bounds__(256) void fill_pairs_kernel(const int2* __restrict__ pairs,
                                                         int* __restrict__ fill,
                                                         int* __restrict__ sorted_src, int E) {
    int i = blockIdx.x * 256 + threadIdx.x;
    if (i < E) {
        int2 p = pairs[i];
        int pos = atomicAdd(&fill[p.y], 1);
        sorted_src[pos] = p.x;
    }
}

// ---------------------------------------------------------------------------
// Fold BN(eval)+conv bias into scale/bias per (layer, feature)
__global__ __launch_bounds__(256) void fold_kernel(const float* __restrict__ gamma,
                                                   const float* __restrict__ beta,
                                                   const float* __restrict__ mean,
                                                   const float* __restrict__ var,
                                                   const float* __restrict__ convb,
                                                   float* __restrict__ scale,
                                                   float* __restrict__ bias, int LH) {
    int i = blockIdx.x * 256 + threadIdx.x;
    if (i < LH) {
        float gs = gamma[i] * rsqrtf(var[i] + 1e-5f);
        scale[i] = gs;
        bias[i] = (convb[i] - mean[i]) * gs + beta[i];
    }
}

// ---------------------------------------------------------------------------
// Pack W[l] into MFMA B-fragment layout, split f16 hi + f16 lo.
__global__ __launch_bounds__(64) void pack_W_kernel(const float* __restrict__ W,
                                                    __half* __restrict__ hi,
                                                    __half* __restrict__ lo) {
    int b = blockIdx.x;         // l*32 + ntile*4 + kchunk
    int l = b >> 5;
    int ntile = (b >> 2) & 7;
    int kchunk = b & 3;
    int lane = threadIdx.x;
    int n = ntile * 16 + (lane & 15);
    int kbase = kchunk * 32 + (lane >> 4) * 8;
    size_t ob = ((size_t)b * 64 + lane) * 8;
#pragma unroll
    for (int j = 0; j < 8; ++j) {
        float w = W[(size_t)l * 16384 + (size_t)(kbase + j) * 128 + n];
        __half hb = __float2half_rn(w);
        float rem = w - __half2float(hb);
        hi[ob + j] = hb;
        lo[ob + j] = __float2half_rn(rem);
    }
}

// ---------------------------------------------------------------------------
// MFMA GEMM (f16, split-W): out16[n] = f16( dis[n] * (h[n] @ W) )
__global__ __launch_bounds__(256) void gemm_mfma_f16(const __half* __restrict__ h16,
                                                     const float* __restrict__ h32,
                                                     const __half* __restrict__ Whi,
                                                     const __half* __restrict__ Wlo,
                                                     const float* __restrict__ dis,
                                                     __half* __restrict__ out, int N) {
    int wave = threadIdx.x >> 6;
    int lane = threadIdx.x & 63;
    int lrow = lane & 15;
    int lk8 = lane >> 4;
    int mbase = blockIdx.x * 128 + wave * 32;

    float4v acc[2][8];
#pragma unroll
    for (int mt = 0; mt < 2; ++mt)
#pragma unroll
        for (int nt = 0; nt < 8; ++nt) {
            acc[mt][nt][0] = 0.f; acc[mt][nt][1] = 0.f;
            acc[mt][nt][2] = 0.f; acc[mt][nt][3] = 0.f;
        }

    const half8v* BH = (const half8v*)Whi;
    const half8v* BL = (const half8v*)Wlo;
    const half8v* H8 = (const half8v*)h16;

    for (int kc = 0; kc < 4; ++kc) {
        half8v a[2];
#pragma unroll
        for (int mt = 0; mt < 2; ++mt) {
            int node = mbase + mt * 16 + lrow;
            if (node < N) {
                if (h32) {
                    const float4* hp = (const float4*)&h32[(size_t)node * HDIM + kc * 32 + lk8 * 8];
                    float4 f0 = hp[0], f1 = hp[1];
                    a[mt][0] = (_Float16)f0.x; a[mt][1] = (_Float16)f0.y;
                    a[mt][2] = (_Float16)f0.z; a[mt][3] = (_Float16)f0.w;
                    a[mt][4] = (_Float16)f1.x; a[mt][5] = (_Float16)f1.y;
                    a[mt][6] = (_Float16)f1.z; a[mt][7] = (_Float16)f1.w;
                } else {
                    a[mt] = H8[(size_t)node * 16 + kc * 4 + lk8];
                }
            } else {
#pragma unroll
                for (int j = 0; j < 8; ++j) a[mt][j] = (_Float16)0;
            }
        }
#pragma unroll
        for (int nt = 0; nt < 8; ++nt) {
            half8v bh = BH[(size_t)(nt * 4 + kc) * 64 + lane];
            half8v bl = BL[(size_t)(nt * 4 + kc) * 64 + lane];
#pragma unroll
            for (int mt = 0; mt < 2; ++mt) {
                acc[mt][nt] = __builtin_amdgcn_mfma_f32_16x16x32_f16(a[mt], bh, acc[mt][nt], 0, 0, 0);
                acc[mt][nt] = __builtin_amdgcn_mfma_f32_16x16x32_f16(a[mt], bl, acc[mt][nt], 0, 0, 0);
            }
        }
    }

#pragma unroll
    for (int mt = 0; mt < 2; ++mt) {
#pragma unroll
        for (int r = 0; r < 4; ++r) {
            int node = mbase + mt * 16 + lk8 * 4 + r;
            if (node < N) {
                float dn = dis[node];
#pragma unroll
                for (int nt = 0; nt < 8; ++nt)
                    out[(size_t)node * HDIM + nt * 16 + lrow] = __float2half_rn(acc[mt][nt][r] * dn);
            }
        }
    }
}

// ---------------------------------------------------------------------------
// Aggregate v2: one wave per node; two half-waves gather two edges per load.
__device__ inline void acc_add8(float4& a, uint2 v) {
    float2 f0 = __half22float2(*(__half2*)&v.x);
    float2 f1 = __half22float2(*(__half2*)&v.y);
    a.x += f0.x; a.y += f0.y; a.z += f1.x; a.w += f1.y;
}

__global__ __launch_bounds__(256) void agg_kernel(const __half* __restrict__ hwp,
                                                  const int* __restrict__ row_ptr,
                                                  const int* __restrict__ ss,
                                                  const float* __restrict__ dis,
                                                  const float* __restrict__ scale,
                                                  const float* __restrict__ bias,
                                                  __half* __restrict__ hout, int N) {
    int wave = threadIdx.x >> 6;
    int lane = threadIdx.x & 63;
    int n = blockIdx.x * 4 + wave;
    if (n >= N) return;
    int hid = lane >> 5;     // which half of the wave
    int l32 = lane & 31;
    const uint2* rows = (const uint2*)hwp;  // row = 32 x uint2 (8B per lane)

    float4 acc0 = make_float4(0.f, 0.f, 0.f, 0.f);
    float4 acc1 = make_float4(0.f, 0.f, 0.f, 0.f);

    // self term: half 0 only
    if (hid == 0) {
        uint2 sv = rows[(size_t)n * 32 + l32];
        acc_add8(acc0, sv);
    }

    int e0 = row_ptr[n];
    int e1 = row_ptr[n + 1];
    int e = e0;
    for (; e + 7 < e1; e += 8) {
        int sA = ss[e], sB = ss[e + 1], sC = ss[e + 2], sD = ss[e + 3];
        int sE = ss[e + 4], sF = ss[e + 5], sG = ss[e + 6], sH = ss[e + 7];
        int q0 = hid ? sB : sA;
        int q1 = hid ? sD : sC;
        int q2 = hid ? sF : sE;
        int q3 = hid ? sH : sG;
        uint2 v0 = rows[(size_t)q0 * 32 + l32];
        uint2 v1 = rows[(size_t)q1 * 32 + l32];
        uint2 v2 = rows[(size_t)q2 * 32 + l32];
        uint2 v3 = rows[(size_t)q3 * 32 + l32];
        acc_add8(acc0, v0);
        acc_add8(acc1, v1);
        acc_add8(acc0, v2);
        acc_add8(acc1, v3);
    }
    for (; e + 1 < e1; e += 2) {
        int sA = ss[e], sB = ss[e + 1];
        int q0 = hid ? sB : sA;
        uint2 v0 = rows[(size_t)q0 * 32 + l32];
        acc_add8(acc0, v0);
    }
    if (e < e1) {
        if (hid == 0) {
            int sA = ss[e];
            uint2 v0 = rows[(size_t)sA * 32 + l32];
            acc_add8(acc1, v0);
        }
    }
    acc0.x += acc1.x; acc0.y += acc1.y; acc0.z += acc1.z; acc0.w += acc1.w;

    acc0.x += __shfl_xor(acc0.x, 32);
    acc0.y += __shfl_xor(acc0.y, 32);
    acc0.z += __shfl_xor(acc0.z, 32);
    acc0.w += __shfl_xor(acc0.w, 32);

    if (hid == 0) {
        float dn = dis[n];
        int f0 = l32 * 4;
        float4 sc = *(const float4*)&scale[f0];
        float4 bs = *(const float4*)&bias[f0];
        float y0 = fmaxf(dn * acc0.x * sc.x + bs.x, 0.f);
        float y1 = fmaxf(dn * acc0.y * sc.y + bs.y, 0.f);
        float y2 = fmaxf(dn * acc0.z * sc.z + bs.z, 0.f);
        float y3 = fmaxf(dn * acc0.w * sc.w + bs.w, 0.f);
        __half2 o0 = __floats2half2_rn(y0, y1);
        __half2 o1 = __floats2half2_rn(y2, y3);
        uint2 ov;
        ov.x = *(unsigned*)&o0;
        ov.y = *(unsigned*)&o1;
        ((uint2*)hout)[(size_t)n * 32 + l32] = ov;
    }
}

// ---------------------------------------------------------------------------
// Global add pool v2: 64 nodes/block, 256 thr = 4 groups x 64 lanes;
// lane owns a half2 feature pair; fp32 accum; flush on graph-run boundary.
__global__ __launch_bounds__(256) void pool_kernel(const __half* __restrict__ h,
                                                   const int* __restrict__ batch,
                                                   float* __restrict__ pooled, int N) {
    int t = threadIdx.x;
    int grp = t >> 6;
    int lane = t & 63;
    int n0 = blockIdx.x * 64 + grp * 16;
    if (n0 >= N) return;
    int nend = n0 + 16; if (nend > N) nend = N;
    const __half2* h2 = (const __half2*)h;

    float2 acc = make_float2(0.f, 0.f);
    int cur = batch[n0];
    for (int n = n0; n < nend; ++n) {
        int gn = batch[n];
        if (gn != cur) {
            atomicAdd(&pooled[cur * HDIM + lane * 2], acc.x);
            atomicAdd(&pooled[cur * HDIM + lane * 2 + 1], acc.y);
            acc = make_float2(0.f, 0.f);
            cur = gn;
        }
        float2 v = __half22float2(h2[(size_t)n * 64 + lane]);
        acc.x += v.x;
        acc.y += v.y;
    }
    atomicAdd(&pooled[cur * HDIM + lane * 2], acc.x);
    atomicAdd(&pooled[cur * HDIM + lane * 2 + 1], acc.y);
}

// ---------------------------------------------------------------------------
// Heads: one block per graph.
__global__ __launch_bounds__(128) void head_kernel(const float* __restrict__ pooled,
                                                   const float* __restrict__ cW1, const float* __restrict__ cb1,
                                                   const float* __restrict__ cW2, const float* __restrict__ cb2,
                                                   const float* __restrict__ nW1, const float* __restrict__ nb1,
                                                   const float* __restrict__ nW2, const float* __restrict__ nb2,
                                                   float* __restrict__ out) {
    __shared__ float p[128];
    __shared__ float hid[128];
    int g = blockIdx.x, t = threadIdx.x;
    p[t] = pooled[g * HDIM + t];
    __syncthreads();

    float a = cb1[t];
    for (int k = 0; k < 128; ++k) a += p[k] * cW1[k * 128 + t];
    hid[t] = fmaxf(a, 0.f);
    __syncthreads();
    if (t < 16) {
        float acc = cb2[t];
        for (int j = 0; j < 128; ++j) acc += hid[j] * cW2[j * 16 + t];
        out[g * 16 + t] = acc;
    }
    __syncthreads();

    float b = nb1[t];
    for (int k = 0; k < 128; ++k) b += p[k] * nW1[k * 128 + t];
    hid[t] = fmaxf(b, 0.f);
    __syncthreads();
    if (t == 0) {
        float acc = nb2[0];
        for (int j = 0; j < 128; ++j) acc += hid[j] * nW2[j];
        out[NUM_GRAPHS * 16 + g] = 1.f / (1.f + expf(-acc));
    }
}

// ---------------------------------------------------------------------------
extern "C" void kernel_launch(void* const* d_in, const int* in_sizes, int n_in,
                              void* d_out, int out_size, void* d_ws, size_t ws_size,
                              hipStream_t stream) {
    const float* x       = (const float*)d_in[0];
    const int*   ei      = (const int*)d_in[1];
    const int*   batch   = (const int*)d_in[2];
    const float* conv_W  = (const float*)d_in[3];
    const float* conv_b  = (const float*)d_in[4];
    const float* bn_g    = (const float*)d_in[5];
    const float* bn_b    = (const float*)d_in[6];
    const float* bn_m    = (const float*)d_in[7];
    const float* bn_v    = (const float*)d_in[8];
    const float* cW1     = (const float*)d_in[9];
    const float* cb1     = (const float*)d_in[10];
    const float* cW2     = (const float*)d_in[11];
    const float* cb2     = (const float*)d_in[12];
    const float* nW1     = (const float*)d_in[13];
    const float* nb1     = (const float*)d_in[14];
    const float* nW2     = (const float*)d_in[15];
    const float* nb2     = (const float*)d_in[16];

    const int N = in_sizes[2];
    const int E = in_sizes[1] / 2;
    const int L = in_sizes[3] / (128 * 128);
    const int H = HDIM;

    const int* src = ei;
    const int* dst = ei + E;

    int shift = 9;
    while ((((N - 1) >> shift) + 1) > 256) ++shift;
    const int NB = ((N - 1) >> shift) + 1;
    const int M = NB * NBLK_S;
    const int chunk = (E + NBLK_S - 1) / NBLK_S;

    char* w = (char*)d_ws;
    size_t o = 0;
    auto alloc = [&](size_t bytes) -> void* {
        void* p = w + o;
        o = (o + bytes + 255) & ~(size_t)255;
        return p;
    };
    int nscanN = (N + 4095) / 4096;
    int nscanM = (M + 4095) / 4096;
    int nscanMax = nscanN > nscanM ? nscanN : nscanM;

    int*    cnt        = (int*)alloc((size_t)N * 4);
    int*    fill       = (int*)alloc((size_t)N * 4);
    int*    row_ptr    = (int*)alloc((size_t)(N + 1) * 4);
    float*  dis        = (float*)alloc((size_t)N * 4);
    float*  scale      = (float*)alloc((size_t)L * H * 4);
    float*  bias       = (float*)alloc((size_t)L * H * 4);
    int*    blockSums  = (int*)alloc((size_t)nscanMax * 4);
    int*    hist       = (int*)alloc((size_t)M * 4);
    int2*   pairs      = (int2*)alloc((size_t)E * 8);
    int*    sorted_src = (int*)alloc((size_t)E * 4);
    __half* Whi        = (__half*)alloc((size_t)L * H * H * 2);
    __half* Wlo        = (__half*)alloc((size_t)L * H * H * 2);
    __half* bufA       = (__half*)alloc((size_t)N * H * 2);  // hw' table
    __half* bufB       = (__half*)alloc((size_t)N * H * 2);  // h
    float*  pooled     = (float*)alloc((size_t)NUM_GRAPHS * H * 4);

    hipMemsetAsync(cnt, 0, (size_t)N * 4, stream);
    hipMemsetAsync(pooled, 0, (size_t)NUM_GRAPHS * H * 4, stream);

    count_hist_kernel<<<NBLK_S, 256, 0, stream>>>(dst, cnt, hist, E, chunk, shift, NB);
    scan_partial_kernel<<<nscanN, 256, 0, stream>>>(cnt, blockSums, N);
    scan_blocksums_kernel<<<1, 1024, 0, stream>>>(blockSums, row_ptr, nscanN, E, N);
    scan_apply_kernel<<<nscanN, 256, 0, stream>>>(cnt, blockSums, row_ptr, fill, dis, N);
    scan_partial_kernel<<<nscanM, 256, 0, stream>>>(hist, blockSums, M);
    scan_blocksums_kernel<<<1, 1024, 0, stream>>>(blockSums, nullptr, nscanM, 0, 0);
    scan_apply_generic<<<nscanM, 256, 0, stream>>>(hist, blockSums, M);
    scatter_bucket_kernel<<<NBLK_S, 256, 0, stream>>>(src, dst, hist, pairs, E, chunk, shift, NB);
    fill_pairs_kernel<<<(E + 255) / 256, 256, 0, stream>>>(pairs, fill, sorted_src, E);

    fold_kernel<<<(L * H + 255) / 256, 256, 0, stream>>>(bn_g, bn_b, bn_m, bn_v, conv_b,
                                                         scale, bias, L * H);
    pack_W_kernel<<<L * 32, 64, 0, stream>>>(conv_W, Whi, Wlo);

    const __half* hin = nullptr;  // layer 0 reads x (fp32) directly
    for (int l = 0; l < L; ++l) {
        gemm_mfma_f16<<<(N + 127) / 128, 256, 0, stream>>>(hin, l == 0 ? x : nullptr,
                                                           Whi + (size_t)l * H * H,
                                                           Wlo + (size_t)l * H * H,
                                                           dis, bufA, N);
        agg_kernel<<<(N + 3) / 4, 256, 0, stream>>>(bufA, row_ptr, sorted_src, dis,
                                                    scale + l * H, bias + l * H, bufB, N);
        hin = bufB;
    }

    pool_kernel<<<(N + 63) / 64, 256, 0, stream>>>(bufB, batch, pooled, N);
    head_kernel<<<NUM_GRAPHS, 128, 0, stream>>>(pooled, cW1, cb1, cW2, cb2,
                                                nW1, nb1, nW2, nb2, (float*)d_out);
}